// Round 1
// baseline (18497.603 us; speedup 1.0000x reference)
//
#include <hip/hip_runtime.h>
#include <hip/hip_bf16.h>
#include <math.h>

// ---------------- problem constants ----------------
#define BATCH 32
#define NTOK  197          // 14*14 + 1
#define NPATCH 196
#define DMODEL 768
#define NLAYER 12
#define NHEAD 12
#define HDIM  64
#define ROWS  (BATCH*NTOK)     // 6304
#define CROWS (BATCH*NPATCH)   // 6272
#define DFF   3072
#define DQKV  2304
#define DOUT  512

// workspace layout (float offsets)
#define WS_H    ((size_t)0)
#define WS_T    ((size_t)(ROWS*DMODEL))                         // 4841472
#define WS_QKV  (WS_T + (size_t)(ROWS*DMODEL))                  // 9682944
#define WS_BIG  (WS_QKV + (size_t)(ROWS*DQKV))                  // 24207360  (max(scores 14.9M, mlp 19.37M))
#define WS_ADD  (WS_BIG + (size_t)(ROWS*DFF))                   // 43573248
#define WS_PT   (WS_ADD + (size_t)38812)                        // 43612060 (16B aligned)

// ---------------- small kernels ----------------

__global__ void im2col_k(const float* __restrict__ x, float* __restrict__ out) {
    int idx = blockIdx.x * 256 + threadIdx.x;
    if (idx >= CROWS * DMODEL) return;
    int r = idx / DMODEL, k = idx - r * DMODEL;
    int b = r / NPATCH, p = r - b * NPATCH;
    int py = p / 14, px = p - py * 14;
    int c = k >> 8, rem = k & 255;
    int i = rem >> 4, j = rem & 15;
    out[idx] = x[(((size_t)(b * 3 + c) * 224) + py * 16 + i) * 224 + px * 16 + j];
}

__global__ void embed_k(const float* __restrict__ conv, const float* __restrict__ cls,
                        const float* __restrict__ pos, float* __restrict__ h) {
    int idx = blockIdx.x * 256 + threadIdx.x;
    if (idx >= ROWS * DMODEL) return;
    int r = idx / DMODEL, d = idx - r * DMODEL;
    int b = r / NTOK, tok = r - b * NTOK;
    float v = (tok == 0) ? cls[d] : conv[((size_t)(b * NPATCH + tok - 1)) * DMODEL + d];
    h[idx] = v + pos[(size_t)tok * DMODEL + d];
}

__global__ void gauss_k(float* __restrict__ add) {
    int idx = blockIdx.x * 256 + threadIdx.x;
    if (idx >= NTOK * NTOK) return;
    int i = idx / NTOK, j = idx - i * NTOK;
    float v = 0.f;
    if (i > 0 && j > 0) {
        int p = i - 1, q = j - 1;
        int di = q / 14 - p / 14;
        int dj = q % 14 - p % 14;
        v = expf(-(float)(di * di + dj * dj) * 0.02f);  // /50
    }
    add[idx] = v;
}

__global__ void transpose_k(const float* __restrict__ in, float* __restrict__ out) {
    // in: [768][512]  -> out: [512][768]
    int idx = blockIdx.x * 256 + threadIdx.x;
    if (idx >= DMODEL * DOUT) return;
    int n = idx / DMODEL, k = idx - n * DMODEL;
    out[idx] = in[(size_t)k * DOUT + n];
}

// LayerNorm over D=768, one block (256 threads) per row. Safe in-place.
__global__ __launch_bounds__(256) void ln768_k(const float* __restrict__ in, float* __restrict__ out,
                                               const float* __restrict__ w, const float* __restrict__ b) {
    int row = blockIdx.x, tid = threadIdx.x;
    const float* x = in + (size_t)row * DMODEL;
    float v0 = x[tid], v1 = x[tid + 256], v2 = x[tid + 512];
    float s = v0 + v1 + v2;
    float s2 = v0 * v0 + v1 * v1 + v2 * v2;
    for (int o = 32; o > 0; o >>= 1) { s += __shfl_down(s, o); s2 += __shfl_down(s2, o); }
    __shared__ float red[8];
    int wid = tid >> 6;
    if ((tid & 63) == 0) { red[wid] = s; red[4 + wid] = s2; }
    __syncthreads();
    s  = red[0] + red[1] + red[2] + red[3];
    s2 = red[4] + red[5] + red[6] + red[7];
    float mean = s * (1.0f / 768.0f);
    float var  = s2 * (1.0f / 768.0f) - mean * mean;
    float rinv = rsqrtf(var + 1e-5f);
    float* o_ = out + (size_t)row * DMODEL;
    o_[tid]       = (v0 - mean) * rinv * w[tid]       + b[tid];
    o_[tid + 256] = (v1 - mean) * rinv * w[tid + 256] + b[tid + 256];
    o_[tid + 512] = (v2 - mean) * rinv * w[tid + 512] + b[tid + 512];
}

// ---------------- fp32 GEMM:  C[M,N] = A[M,K] @ W[N,K]^T (+bias) ----------------
// mode 0: store; mode 1: quick_gelu then store; mode 2: C += result (residual)
__global__ __launch_bounds__(256) void gemm_nt_k(
    const float* __restrict__ A, const float* __restrict__ W,
    const float* __restrict__ bias, float* __restrict__ C,
    int M, int N, int K, int mode)
{
    __shared__ float As[16][132];
    __shared__ float Bs[16][132];
    int tid = threadIdx.x;
    int m0 = blockIdx.y * 128, n0 = blockIdx.x * 128;
    int tx = tid & 15, ty = tid >> 4;
    float acc[8][8];
    #pragma unroll
    for (int i = 0; i < 8; ++i)
        #pragma unroll
        for (int j = 0; j < 8; ++j) acc[i][j] = 0.f;

    int lr = tid >> 2;           // 0..63
    int lk = (tid & 3) * 4;      // 0,4,8,12
    const float* Aptr = A + (size_t)(m0 + lr) * K + lk;
    const float* Wptr = W + (size_t)(n0 + lr) * K + lk;
    bool am0 = (m0 + lr) < M;
    bool am1 = (m0 + lr + 64) < M;

    for (int k0 = 0; k0 < K; k0 += 16) {
        float4 a0 = {0,0,0,0}, a1 = {0,0,0,0};
        if (am0) a0 = *(const float4*)(Aptr + k0);
        if (am1) a1 = *(const float4*)(Aptr + (size_t)64 * K + k0);
        float4 b0 = *(const float4*)(Wptr + k0);
        float4 b1 = *(const float4*)(Wptr + (size_t)64 * K + k0);
        __syncthreads();
        As[lk + 0][lr] = a0.x; As[lk + 1][lr] = a0.y; As[lk + 2][lr] = a0.z; As[lk + 3][lr] = a0.w;
        As[lk + 0][lr + 64] = a1.x; As[lk + 1][lr + 64] = a1.y; As[lk + 2][lr + 64] = a1.z; As[lk + 3][lr + 64] = a1.w;
        Bs[lk + 0][lr] = b0.x; Bs[lk + 1][lr] = b0.y; Bs[lk + 2][lr] = b0.z; Bs[lk + 3][lr] = b0.w;
        Bs[lk + 0][lr + 64] = b1.x; Bs[lk + 1][lr + 64] = b1.y; Bs[lk + 2][lr + 64] = b1.z; Bs[lk + 3][lr + 64] = b1.w;
        __syncthreads();
        #pragma unroll
        for (int k = 0; k < 16; ++k) {
            float4 aA = *(const float4*)&As[k][ty * 8];
            float4 aB = *(const float4*)&As[k][ty * 8 + 4];
            float4 bA = *(const float4*)&Bs[k][tx * 8];
            float4 bB = *(const float4*)&Bs[k][tx * 8 + 4];
            float av[8] = {aA.x, aA.y, aA.z, aA.w, aB.x, aB.y, aB.z, aB.w};
            float bv[8] = {bA.x, bA.y, bA.z, bA.w, bB.x, bB.y, bB.z, bB.w};
            #pragma unroll
            for (int i = 0; i < 8; ++i)
                #pragma unroll
                for (int j = 0; j < 8; ++j)
                    acc[i][j] = fmaf(av[i], bv[j], acc[i][j]);
        }
    }

    int colbase = n0 + tx * 8;
    float bsv[8];
    #pragma unroll
    for (int jj = 0; jj < 8; ++jj) bsv[jj] = bias ? bias[colbase + jj] : 0.f;
    #pragma unroll
    for (int i = 0; i < 8; ++i) {
        int row = m0 + ty * 8 + i;
        if (row < M) {
            float* Cp = C + (size_t)row * N + colbase;
            #pragma unroll
            for (int jh = 0; jh < 2; ++jh) {
                float r[4];
                #pragma unroll
                for (int c = 0; c < 4; ++c) r[c] = acc[i][jh * 4 + c] + bsv[jh * 4 + c];
                if (mode == 1) {
                    #pragma unroll
                    for (int c = 0; c < 4; ++c) r[c] = r[c] / (1.0f + expf(-1.702f * r[c]));
                } else if (mode == 2) {
                    float4 old = *(const float4*)(Cp + jh * 4);
                    r[0] += old.x; r[1] += old.y; r[2] += old.z; r[3] += old.w;
                }
                float4 st = {r[0], r[1], r[2], r[3]};
                *(float4*)(Cp + jh * 4) = st;
            }
        }
    }
}

// ---------------- attention ----------------
// scores: S[bh][i][j] = dot(Q[i],K[j]) * 0.125 (+addition)   Q from qkv col-offset qoff
__global__ __launch_bounds__(256) void attn_scores_k(
    const float* __restrict__ qkv, float* __restrict__ S,
    const float* __restrict__ addition, int qoff)
{
    int bh = blockIdx.y;
    int b = bh / NHEAD, hh = bh - b * NHEAD;
    int i0 = blockIdx.x * 16;
    int tid = threadIdx.x;
    int tj = tid & 15, ti = tid >> 4;
    __shared__ float Qs[16][64];
    __shared__ float Ks[16][68];
    int lrow = tid >> 4, d4 = (tid & 15) * 4;
    {
        int qrow = i0 + lrow;
        float4 qv = {0,0,0,0};
        if (qrow < NTOK) qv = *(const float4*)(qkv + ((size_t)(b * NTOK + qrow)) * DQKV + qoff + hh * HDIM + d4);
        *(float4*)&Qs[lrow][d4] = qv;
    }
    float* Sbase = S + (size_t)bh * NTOK * NTOK;
    for (int jt = 0; jt < 13; ++jt) {
        int j0 = jt * 16;
        int krow = j0 + lrow;
        float4 kv = {0,0,0,0};
        if (krow < NTOK) kv = *(const float4*)(qkv + ((size_t)(b * NTOK + krow)) * DQKV + DMODEL + hh * HDIM + d4);
        __syncthreads();
        *(float4*)&Ks[lrow][d4] = kv;
        __syncthreads();
        float acc = 0.f;
        #pragma unroll
        for (int dq = 0; dq < 16; ++dq) {
            float4 q4 = *(const float4*)&Qs[ti][dq * 4];
            float4 k4 = *(const float4*)&Ks[tj][dq * 4];
            acc += q4.x * k4.x + q4.y * k4.y + q4.z * k4.z + q4.w * k4.w;
        }
        int irow = i0 + ti, jcol = j0 + tj;
        if (irow < NTOK && jcol < NTOK) {
            float v = acc * 0.125f;
            if (addition) v += addition[irow * NTOK + jcol];
            Sbase[(size_t)irow * NTOK + jcol] = v;
        }
    }
}

__global__ __launch_bounds__(64) void softmax197_k(float* __restrict__ S) {
    size_t row = blockIdx.x;
    float* p = S + row * NTOK;
    int lane = threadIdx.x;
    float v[4], e[4];
    float mx = -1e30f;
    #pragma unroll
    for (int c = 0; c < 4; ++c) {
        int j = lane + c * 64;
        v[c] = (j < NTOK) ? p[j] : -1e30f;
        mx = fmaxf(mx, v[c]);
    }
    for (int o = 32; o > 0; o >>= 1) mx = fmaxf(mx, __shfl_xor(mx, o));
    float sum = 0.f;
    #pragma unroll
    for (int c = 0; c < 4; ++c) { e[c] = expf(v[c] - mx); sum += e[c]; }
    for (int o = 32; o > 0; o >>= 1) sum += __shfl_xor(sum, o);
    float inv = 1.0f / sum;
    #pragma unroll
    for (int c = 0; c < 4; ++c) {
        int j = lane + c * 64;
        if (j < NTOK) p[j] = e[c] * inv;
    }
}

__global__ __launch_bounds__(256) void attn_pv_k(
    const float* __restrict__ S, const float* __restrict__ qkv, float* __restrict__ out)
{
    int bh = blockIdx.y;
    int b = bh / NHEAD, hh = bh - b * NHEAD;
    int i0 = blockIdx.x * 16;
    int tid = threadIdx.x;
    int td = tid & 15, ti = tid >> 4;
    __shared__ float Vs[16][64];
    __shared__ float Ps[16][16];
    float4 acc = {0,0,0,0};
    const float* Sbase = S + (size_t)bh * NTOK * NTOK;
    int lrow = tid >> 4, d4 = (tid & 15) * 4;
    for (int jt = 0; jt < 13; ++jt) {
        int j0 = jt * 16;
        float4 vv = {0,0,0,0};
        int vrow = j0 + lrow;
        if (vrow < NTOK) vv = *(const float4*)(qkv + ((size_t)(b * NTOK + vrow)) * DQKV + 2 * DMODEL + hh * HDIM + d4);
        float pv = 0.f;
        int irow = i0 + ti, jcol = j0 + td;
        if (irow < NTOK && jcol < NTOK) pv = Sbase[(size_t)irow * NTOK + jcol];
        __syncthreads();
        *(float4*)&Vs[lrow][d4] = vv;
        Ps[ti][td] = pv;
        __syncthreads();
        #pragma unroll
        for (int jj = 0; jj < 16; ++jj) {
            float pp = Ps[ti][jj];
            float4 vr = *(const float4*)&Vs[jj][td * 4];
            acc.x = fmaf(pp, vr.x, acc.x);
            acc.y = fmaf(pp, vr.y, acc.y);
            acc.z = fmaf(pp, vr.z, acc.z);
            acc.w = fmaf(pp, vr.w, acc.w);
        }
    }
    int irow = i0 + ti;
    if (irow < NTOK)
        *(float4*)(out + ((size_t)(b * NTOK + irow)) * DMODEL + hh * HDIM + td * 4) = acc;
}

// ---------------- launch ----------------
extern "C" void kernel_launch(void* const* d_in, const int* in_sizes, int n_in,
                              void* d_out, int out_size, void* d_ws, size_t ws_size,
                              hipStream_t stream) {
    const float* x        = (const float*)d_in[0];
    const float* conv1_w  = (const float*)d_in[1];
    const float* cls      = (const float*)d_in[2];
    const float* pos      = (const float*)d_in[3];
    const float* ln_pre_w = (const float*)d_in[4];
    const float* ln_pre_b = (const float*)d_in[5];
    const float* in_proj_w  = (const float*)d_in[6];
    const float* in_proj_b  = (const float*)d_in[7];
    const float* out_proj_w = (const float*)d_in[8];
    const float* out_proj_b = (const float*)d_in[9];
    const float* ln1_w = (const float*)d_in[10];
    const float* ln1_b = (const float*)d_in[11];
    const float* ln2_w = (const float*)d_in[12];
    const float* ln2_b = (const float*)d_in[13];
    const float* fc_w  = (const float*)d_in[14];
    const float* fc_b  = (const float*)d_in[15];
    const float* cproj_w = (const float*)d_in[16];
    const float* cproj_b = (const float*)d_in[17];
    const float* ln_post_w = (const float*)d_in[18];
    const float* ln_post_b = (const float*)d_in[19];
    const float* proj = (const float*)d_in[20];
    float* out = (float*)d_out;

    float* ws  = (float*)d_ws;
    float* h   = ws + WS_H;
    float* t   = ws + WS_T;
    float* qkv = ws + WS_QKV;
    float* big = ws + WS_BIG;
    float* add = ws + WS_ADD;
    float* pT  = ws + WS_PT;

    // patch embedding: im2col -> GEMM -> embed -> ln_pre
    im2col_k<<<(CROWS * DMODEL + 255) / 256, 256, 0, stream>>>(x, qkv);
    gemm_nt_k<<<dim3(DMODEL / 128, CROWS / 128), 256, 0, stream>>>(qkv, conv1_w, nullptr, t,
                                                                   CROWS, DMODEL, DMODEL, 0);
    embed_k<<<(ROWS * DMODEL + 255) / 256, 256, 0, stream>>>(t, cls, pos, h);
    ln768_k<<<ROWS, 256, 0, stream>>>(h, h, ln_pre_w, ln_pre_b);
    gauss_k<<<(NTOK * NTOK + 255) / 256, 256, 0, stream>>>(add);
    transpose_k<<<(DMODEL * DOUT + 255) / 256, 256, 0, stream>>>(proj, pT);

    const int GY = (ROWS + 127) / 128;  // 50
    for (int l = 0; l < NLAYER; ++l) {
        ln768_k<<<ROWS, 256, 0, stream>>>(h, t, ln1_w + l * DMODEL, ln1_b + l * DMODEL);
        gemm_nt_k<<<dim3(DQKV / 128, GY), 256, 0, stream>>>(t, in_proj_w + (size_t)l * DQKV * DMODEL,
                                                            in_proj_b + (size_t)l * DQKV, qkv,
                                                            ROWS, DQKV, DMODEL, 0);
        bool nac = (l == NLAYER - 1);
        attn_scores_k<<<dim3(13, BATCH * NHEAD), 256, 0, stream>>>(qkv, big, nac ? add : nullptr,
                                                                   nac ? DMODEL : 0);
        softmax197_k<<<BATCH * NHEAD * NTOK, 64, 0, stream>>>(big);
        attn_pv_k<<<dim3(13, BATCH * NHEAD), 256, 0, stream>>>(big, qkv, t);
        gemm_nt_k<<<dim3(DMODEL / 128, GY), 256, 0, stream>>>(t, out_proj_w + (size_t)l * DMODEL * DMODEL,
                                                              out_proj_b + (size_t)l * DMODEL, h,
                                                              ROWS, DMODEL, DMODEL, 2);
        ln768_k<<<ROWS, 256, 0, stream>>>(h, t, ln2_w + l * DMODEL, ln2_b + l * DMODEL);
        gemm_nt_k<<<dim3(DFF / 128, GY), 256, 0, stream>>>(t, fc_w + (size_t)l * DFF * DMODEL,
                                                           fc_b + (size_t)l * DFF, big,
                                                           ROWS, DFF, DMODEL, 1);
        gemm_nt_k<<<dim3(DMODEL / 128, GY), 256, 0, stream>>>(big, cproj_w + (size_t)l * DMODEL * DFF,
                                                              cproj_b + (size_t)l * DMODEL, h,
                                                              ROWS, DMODEL, DFF, 2);
    }

    ln768_k<<<ROWS, 256, 0, stream>>>(h, t, ln_post_w, ln_post_b);
    gemm_nt_k<<<dim3(DOUT / 128, GY), 256, 0, stream>>>(t, pT, nullptr, out,
                                                        ROWS, DOUT, DMODEL, 0);
}

// Round 2
// 8103.567 us; speedup vs baseline: 2.2826x; 2.2826x over previous
//
#include <hip/hip_runtime.h>
#include <hip/hip_bf16.h>
#include <math.h>

// ---------------- problem constants ----------------
#define BATCH 32
#define NTOK  197
#define NPATCH 196
#define DMODEL 768
#define NLAYER 12
#define NHEAD 12
#define HDIM  64
#define ROWS  (BATCH*NTOK)     // 6304
#define CROWS (BATCH*NPATCH)   // 6272
#define DFF   3072
#define DQKV  2304
#define DOUT  512
#define NBH   (BATCH*NHEAD)

// workspace layout (float units)
#define WS_H    ((size_t)0)
#define WS_QKV  ((size_t)ROWS*DMODEL)                    // h: ROWS*768 f32
#define WS_SC   (WS_QKV + (size_t)ROWS*DQKV)             // qkv f32
#define WS_TB   (WS_SC + (size_t)NBH*NTOK*NTOK)          // scores f32 / conv tmp
#define WS_GB   (WS_TB + (size_t)ROWS*DMODEL)            // tb: ROWS*1536 bf16
#define WS_WB   (WS_GB + (size_t)ROWS*DFF)               // gb: ROWS*6144 bf16
#define WS_PTS  (WS_WB + (size_t)DFF*DMODEL)             // wbuf: max 4.7M bf16
#define WS_ADD  (WS_PTS + (size_t)DOUT*DMODEL)           // pTs: 512*1536 bf16

typedef unsigned short ushort_t;
typedef __attribute__((ext_vector_type(8))) short bf16x8;
typedef __attribute__((ext_vector_type(4))) float f32x4;

// ---------------- bf16 split helpers ----------------
__device__ inline ushort_t bf16rn(float x) {
    uint32_t u = __builtin_bit_cast(uint32_t, x);
    uint32_t r = (u + 0x7FFFu + ((u >> 16) & 1u)) >> 16;
    return (ushort_t)r;
}
__device__ inline float bf16tof(ushort_t h) {
    return __builtin_bit_cast(float, (uint32_t)h << 16);
}
__device__ inline void split2(float x, ushort_t& hi, ushort_t& lo) {
    hi = bf16rn(x);
    lo = bf16rn(x - bf16tof(hi));
}

// ---------------- small kernels ----------------

// x [32,3,224,224] -> gb split bf16 [6272][1536]
__global__ void im2col_split_k(const float* __restrict__ x, ushort_t* __restrict__ out) {
    int idx = blockIdx.x * 256 + threadIdx.x;
    if (idx >= CROWS * DMODEL / 4) return;
    int r  = idx / (DMODEL / 4);
    int k4 = (idx - r * (DMODEL / 4)) * 4;
    int b = r / NPATCH, p = r - b * NPATCH;
    int py = p / 14, px = p - py * 14;
    int c = k4 >> 8, rem = k4 & 255, i = rem >> 4, j = rem & 15;
    const float* xp = x + (((size_t)(b * 3 + c) * 224) + py * 16 + i) * 224 + px * 16 + j;
    float4 v = *(const float4*)xp;
    ushort_t h0,h1,h2,h3,l0,l1,l2,l3;
    split2(v.x,h0,l0); split2(v.y,h1,l1); split2(v.z,h2,l2); split2(v.w,h3,l3);
    ushort4 hv = {h0,h1,h2,h3}, lv = {l0,l1,l2,l3};
    *(ushort4*)(out + (size_t)r * (2*DMODEL) + k4) = hv;
    *(ushort4*)(out + (size_t)r * (2*DMODEL) + DMODEL + k4) = lv;
}

// W fp32 [N,K] -> out split bf16 [N][2K]
__global__ void cvt_w_k(const float* __restrict__ W, ushort_t* __restrict__ out, int NK, int K) {
    int idx = (blockIdx.x * 256 + threadIdx.x) * 4;
    if (idx >= NK) return;
    float4 v = *(const float4*)(W + idx);
    int n = idx / K, k = idx - n * K;
    ushort_t h0,h1,h2,h3,l0,l1,l2,l3;
    split2(v.x,h0,l0); split2(v.y,h1,l1); split2(v.z,h2,l2); split2(v.w,h3,l3);
    ushort4 hv = {h0,h1,h2,h3}, lv = {l0,l1,l2,l3};
    *(ushort4*)(out + (size_t)n * 2 * K + k) = hv;
    *(ushort4*)(out + (size_t)n * 2 * K + K + k) = lv;
}

// proj [768][512] -> pTs split bf16 [512][1536]
__global__ void cvt_pT_k(const float* __restrict__ proj, ushort_t* __restrict__ out) {
    int idx = blockIdx.x * 256 + threadIdx.x;
    if (idx >= DOUT * DMODEL) return;
    int n = idx / DMODEL, k = idx - n * DMODEL;
    float v = proj[(size_t)k * DOUT + n];
    ushort_t hi, lo; split2(v, hi, lo);
    out[(size_t)n * (2*DMODEL) + k] = hi;
    out[(size_t)n * (2*DMODEL) + DMODEL + k] = lo;
}

__global__ void embed_k(const float* __restrict__ conv, const float* __restrict__ cls,
                        const float* __restrict__ pos, float* __restrict__ h) {
    int idx = blockIdx.x * 256 + threadIdx.x;
    if (idx >= ROWS * DMODEL) return;
    int r = idx / DMODEL, d = idx - r * DMODEL;
    int b = r / NTOK, tok = r - b * NTOK;
    float v = (tok == 0) ? cls[d] : conv[((size_t)(b * NPATCH + tok - 1)) * DMODEL + d];
    h[idx] = v + pos[(size_t)tok * DMODEL + d];
}

__global__ void gauss_k(float* __restrict__ add) {
    int idx = blockIdx.x * 256 + threadIdx.x;
    if (idx >= NTOK * NTOK) return;
    int i = idx / NTOK, j = idx - i * NTOK;
    float v = 0.f;
    if (i > 0 && j > 0) {
        int p = i - 1, q = j - 1;
        int di = q / 14 - p / 14;
        int dj = q % 14 - p % 14;
        v = expf(-(float)(di * di + dj * dj) * 0.02f);
    }
    add[idx] = v;
}

// LayerNorm fp32 in-place (ln_pre)
__global__ __launch_bounds__(256) void ln768_k(const float* __restrict__ in, float* __restrict__ out,
                                               const float* __restrict__ w, const float* __restrict__ b) {
    int row = blockIdx.x, tid = threadIdx.x;
    const float* x = in + (size_t)row * DMODEL;
    float v0 = x[tid], v1 = x[tid + 256], v2 = x[tid + 512];
    float s = v0 + v1 + v2;
    float s2 = v0 * v0 + v1 * v1 + v2 * v2;
    for (int o = 32; o > 0; o >>= 1) { s += __shfl_down(s, o); s2 += __shfl_down(s2, o); }
    __shared__ float red[8];
    int wid = tid >> 6;
    if ((tid & 63) == 0) { red[wid] = s; red[4 + wid] = s2; }
    __syncthreads();
    s  = red[0] + red[1] + red[2] + red[3];
    s2 = red[4] + red[5] + red[6] + red[7];
    float mean = s * (1.0f / 768.0f);
    float var  = s2 * (1.0f / 768.0f) - mean * mean;
    float rinv = rsqrtf(var + 1e-5f);
    float* o_ = out + (size_t)row * DMODEL;
    o_[tid]       = (v0 - mean) * rinv * w[tid]       + b[tid];
    o_[tid + 256] = (v1 - mean) * rinv * w[tid + 256] + b[tid + 256];
    o_[tid + 512] = (v2 - mean) * rinv * w[tid + 512] + b[tid + 512];
}

// LayerNorm fp32 -> split bf16 [row][1536]
__global__ __launch_bounds__(256) void ln768_split_k(const float* __restrict__ in, ushort_t* __restrict__ out,
                                                     const float* __restrict__ w, const float* __restrict__ b) {
    int row = blockIdx.x, tid = threadIdx.x;
    const float* x = in + (size_t)row * DMODEL;
    float v0 = x[tid], v1 = x[tid + 256], v2 = x[tid + 512];
    float s = v0 + v1 + v2;
    float s2 = v0 * v0 + v1 * v1 + v2 * v2;
    for (int o = 32; o > 0; o >>= 1) { s += __shfl_down(s, o); s2 += __shfl_down(s2, o); }
    __shared__ float red[8];
    int wid = tid >> 6;
    if ((tid & 63) == 0) { red[wid] = s; red[4 + wid] = s2; }
    __syncthreads();
    s  = red[0] + red[1] + red[2] + red[3];
    s2 = red[4] + red[5] + red[6] + red[7];
    float mean = s * (1.0f / 768.0f);
    float var  = s2 * (1.0f / 768.0f) - mean * mean;
    float rinv = rsqrtf(var + 1e-5f);
    ushort_t* o_ = out + (size_t)row * (2*DMODEL);
    #pragma unroll
    for (int c = 0; c < 3; ++c) {
        int d = tid + c * 256;
        float vv = (c == 0 ? v0 : (c == 1 ? v1 : v2));
        float y = (vv - mean) * rinv * w[d] + b[d];
        ushort_t hi, lo; split2(y, hi, lo);
        o_[d] = hi; o_[DMODEL + d] = lo;
    }
}

// ---------------- MFMA GEMM:  C[M,N] (+)= A[M,K2]bf16 @ W[N,K2]bf16^T ----------------
// mode 0: C = r + bias ; mode 2: C += r + bias ; mode 1: OS = split_bf16(quick_gelu(r+bias))
__global__ __launch_bounds__(256) void gemm_mfma_k(
    const ushort_t* __restrict__ A, const ushort_t* __restrict__ W,
    const float* __restrict__ bias, float* __restrict__ C, ushort_t* __restrict__ OS,
    int M, int N, int K2, int mode)
{
    __shared__ ushort_t As[128][32];
    __shared__ ushort_t Bs[128][32];
    int tid = threadIdx.x;
    int lane = tid & 63;
    int wave = tid >> 6;
    int wm = wave >> 1, wn = wave & 1;
    int m0 = blockIdx.y * 128, n0 = blockIdx.x * 128;

    f32x4 acc[4][4];
    #pragma unroll
    for (int i = 0; i < 4; ++i)
        #pragma unroll
        for (int j = 0; j < 4; ++j)
            acc[i][j] = (f32x4){0.f, 0.f, 0.f, 0.f};

    int srow = tid >> 2;         // 0..63
    int skq  = (tid & 3) * 8;    // bf16 elem offset
    int ar0 = m0 + srow;     if (ar0 > M - 1) ar0 = M - 1;
    int ar1 = m0 + srow + 64; if (ar1 > M - 1) ar1 = M - 1;
    const ushort_t* Ap0 = A + (size_t)ar0 * K2 + skq;
    const ushort_t* Ap1 = A + (size_t)ar1 * K2 + skq;
    const ushort_t* Wp0 = W + (size_t)(n0 + srow) * K2 + skq;
    const ushort_t* Wp1 = W + (size_t)(n0 + srow + 64) * K2 + skq;
    char* ldsA0 = (char*)&As[0][0] + tid * 16;
    char* ldsA1 = ldsA0 + 4096;
    char* ldsB0 = (char*)&Bs[0][0] + tid * 16;
    char* ldsB1 = ldsB0 + 4096;

    int fr = lane & 15, fq = lane >> 4;

    for (int k0 = 0; k0 < K2; k0 += 32) {
        __builtin_amdgcn_global_load_lds((const __attribute__((address_space(1))) void*)(Ap0 + k0),
                                         (__attribute__((address_space(3))) void*)ldsA0, 16, 0, 0);
        __builtin_amdgcn_global_load_lds((const __attribute__((address_space(1))) void*)(Ap1 + k0),
                                         (__attribute__((address_space(3))) void*)ldsA1, 16, 0, 0);
        __builtin_amdgcn_global_load_lds((const __attribute__((address_space(1))) void*)(Wp0 + k0),
                                         (__attribute__((address_space(3))) void*)ldsB0, 16, 0, 0);
        __builtin_amdgcn_global_load_lds((const __attribute__((address_space(1))) void*)(Wp1 + k0),
                                         (__attribute__((address_space(3))) void*)ldsB1, 16, 0, 0);
        __syncthreads();   // drains vmcnt before use

        bf16x8 a[4], b[4];
        #pragma unroll
        for (int fm = 0; fm < 4; ++fm)
            a[fm] = *(const bf16x8*)&As[wm * 64 + fm * 16 + fr][fq * 8];
        #pragma unroll
        for (int fn = 0; fn < 4; ++fn)
            b[fn] = *(const bf16x8*)&Bs[wn * 64 + fn * 16 + fr][fq * 8];
        #pragma unroll
        for (int fm = 0; fm < 4; ++fm)
            #pragma unroll
            for (int fn = 0; fn < 4; ++fn)
                acc[fm][fn] = __builtin_amdgcn_mfma_f32_16x16x32_bf16(a[fm], b[fn], acc[fm][fn], 0, 0, 0);
        __syncthreads();   // all reads done before next stage
    }

    // epilogue: D col = lane&15 (fr), row = fq*4 + j   [m89-verified layout]
    #pragma unroll
    for (int fn = 0; fn < 4; ++fn) {
        int ccol = n0 + wn * 64 + fn * 16 + fr;
        float bv = bias ? bias[ccol] : 0.f;
        #pragma unroll
        for (int fm = 0; fm < 4; ++fm) {
            int crow0 = m0 + wm * 64 + fm * 16 + fq * 4;
            #pragma unroll
            for (int j = 0; j < 4; ++j) {
                int row = crow0 + j;
                if (row < M) {
                    float v = acc[fm][fn][j] + bv;
                    if (mode == 0) {
                        C[(size_t)row * N + ccol] = v;
                    } else if (mode == 2) {
                        C[(size_t)row * N + ccol] += v;
                    } else {
                        v = v / (1.0f + expf(-1.702f * v));
                        ushort_t hi, lo; split2(v, hi, lo);
                        OS[(size_t)row * 2 * N + ccol] = hi;
                        OS[(size_t)row * 2 * N + N + ccol] = lo;
                    }
                }
            }
        }
    }
}

// ---------------- attention (fp32 VALU) ----------------
__global__ __launch_bounds__(256) void attn_scores_k(
    const float* __restrict__ qkv, float* __restrict__ S,
    const float* __restrict__ addition, int qoff)
{
    int bh = blockIdx.y;
    int b = bh / NHEAD, hh = bh - b * NHEAD;
    int i0 = blockIdx.x * 16;
    int tid = threadIdx.x;
    int tj = tid & 15, ti = tid >> 4;
    __shared__ float Qs[16][64];
    __shared__ float Ks[16][68];
    int lrow = tid >> 4, d4 = (tid & 15) * 4;
    {
        int qrow = i0 + lrow;
        float4 qv = {0,0,0,0};
        if (qrow < NTOK) qv = *(const float4*)(qkv + ((size_t)(b * NTOK + qrow)) * DQKV + qoff + hh * HDIM + d4);
        *(float4*)&Qs[lrow][d4] = qv;
    }
    float* Sbase = S + (size_t)bh * NTOK * NTOK;
    for (int jt = 0; jt < 13; ++jt) {
        int j0 = jt * 16;
        int krow = j0 + lrow;
        float4 kv = {0,0,0,0};
        if (krow < NTOK) kv = *(const float4*)(qkv + ((size_t)(b * NTOK + krow)) * DQKV + DMODEL + hh * HDIM + d4);
        __syncthreads();
        *(float4*)&Ks[lrow][d4] = kv;
        __syncthreads();
        float acc = 0.f;
        #pragma unroll
        for (int dq = 0; dq < 16; ++dq) {
            float4 q4 = *(const float4*)&Qs[ti][dq * 4];
            float4 k4 = *(const float4*)&Ks[tj][dq * 4];
            acc += q4.x * k4.x + q4.y * k4.y + q4.z * k4.z + q4.w * k4.w;
        }
        int irow = i0 + ti, jcol = j0 + tj;
        if (irow < NTOK && jcol < NTOK) {
            float v = acc * 0.125f;
            if (addition) v += addition[irow * NTOK + jcol];
            Sbase[(size_t)irow * NTOK + jcol] = v;
        }
    }
}

__global__ __launch_bounds__(64) void softmax197_k(float* __restrict__ S) {
    size_t row = blockIdx.x;
    float* p = S + row * NTOK;
    int lane = threadIdx.x;
    float v[4], e[4];
    float mx = -1e30f;
    #pragma unroll
    for (int c = 0; c < 4; ++c) {
        int j = lane + c * 64;
        v[c] = (j < NTOK) ? p[j] : -1e30f;
        mx = fmaxf(mx, v[c]);
    }
    for (int o = 32; o > 0; o >>= 1) mx = fmaxf(mx, __shfl_xor(mx, o));
    float sum = 0.f;
    #pragma unroll
    for (int c = 0; c < 4; ++c) { e[c] = expf(v[c] - mx); sum += e[c]; }
    for (int o = 32; o > 0; o >>= 1) sum += __shfl_xor(sum, o);
    float inv = 1.0f / sum;
    #pragma unroll
    for (int c = 0; c < 4; ++c) {
        int j = lane + c * 64;
        if (j < NTOK) p[j] = e[c] * inv;
    }
}

// PV -> split bf16 into tb [row][1536]
__global__ __launch_bounds__(256) void attn_pv_split_k(
    const float* __restrict__ S, const float* __restrict__ qkv, ushort_t* __restrict__ out)
{
    int bh = blockIdx.y;
    int b = bh / NHEAD, hh = bh - b * NHEAD;
    int i0 = blockIdx.x * 16;
    int tid = threadIdx.x;
    int td = tid & 15, ti = tid >> 4;
    __shared__ float Vs[16][64];
    __shared__ float Ps[16][16];
    float4 acc = {0,0,0,0};
    const float* Sbase = S + (size_t)bh * NTOK * NTOK;
    int lrow = tid >> 4, d4 = (tid & 15) * 4;
    for (int jt = 0; jt < 13; ++jt) {
        int j0 = jt * 16;
        float4 vv = {0,0,0,0};
        int vrow = j0 + lrow;
        if (vrow < NTOK) vv = *(const float4*)(qkv + ((size_t)(b * NTOK + vrow)) * DQKV + 2 * DMODEL + hh * HDIM + d4);
        float pv = 0.f;
        int irow = i0 + ti, jcol = j0 + td;
        if (irow < NTOK && jcol < NTOK) pv = Sbase[(size_t)irow * NTOK + jcol];
        __syncthreads();
        *(float4*)&Vs[lrow][d4] = vv;
        Ps[ti][td] = pv;
        __syncthreads();
        #pragma unroll
        for (int jj = 0; jj < 16; ++jj) {
            float pp = Ps[ti][jj];
            float4 vr = *(const float4*)&Vs[jj][td * 4];
            acc.x = fmaf(pp, vr.x, acc.x);
            acc.y = fmaf(pp, vr.y, acc.y);
            acc.z = fmaf(pp, vr.z, acc.z);
            acc.w = fmaf(pp, vr.w, acc.w);
        }
    }
    int irow = i0 + ti;
    if (irow < NTOK) {
        ushort_t h0,h1,h2,h3,l0,l1,l2,l3;
        split2(acc.x,h0,l0); split2(acc.y,h1,l1); split2(acc.z,h2,l2); split2(acc.w,h3,l3);
        ushort4 hv = {h0,h1,h2,h3}, lv = {l0,l1,l2,l3};
        ushort_t* op = out + ((size_t)(b * NTOK + irow)) * (2*DMODEL) + hh * HDIM + td * 4;
        *(ushort4*)op = hv;
        *(ushort4*)(op + DMODEL) = lv;
    }
}

// ---------------- launch ----------------
extern "C" void kernel_launch(void* const* d_in, const int* in_sizes, int n_in,
                              void* d_out, int out_size, void* d_ws, size_t ws_size,
                              hipStream_t stream) {
    const float* x        = (const float*)d_in[0];
    const float* conv1_w  = (const float*)d_in[1];
    const float* cls      = (const float*)d_in[2];
    const float* pos      = (const float*)d_in[3];
    const float* ln_pre_w = (const float*)d_in[4];
    const float* ln_pre_b = (const float*)d_in[5];
    const float* in_proj_w  = (const float*)d_in[6];
    const float* in_proj_b  = (const float*)d_in[7];
    const float* out_proj_w = (const float*)d_in[8];
    const float* out_proj_b = (const float*)d_in[9];
    const float* ln1_w = (const float*)d_in[10];
    const float* ln1_b = (const float*)d_in[11];
    const float* ln2_w = (const float*)d_in[12];
    const float* ln2_b = (const float*)d_in[13];
    const float* fc_w  = (const float*)d_in[14];
    const float* fc_b  = (const float*)d_in[15];
    const float* cproj_w = (const float*)d_in[16];
    const float* cproj_b = (const float*)d_in[17];
    const float* ln_post_w = (const float*)d_in[18];
    const float* ln_post_b = (const float*)d_in[19];
    const float* proj = (const float*)d_in[20];
    float* out = (float*)d_out;

    float* ws  = (float*)d_ws;
    float* h    = ws + WS_H;
    float* qkv  = ws + WS_QKV;
    float* sc   = ws + WS_SC;
    ushort_t* tb   = (ushort_t*)(ws + WS_TB);
    ushort_t* gb   = (ushort_t*)(ws + WS_GB);
    ushort_t* wbuf = (ushort_t*)(ws + WS_WB);
    ushort_t* pTs  = (ushort_t*)(ws + WS_PTS);
    float* add  = ws + WS_ADD;

    // patch embedding: im2col(split) -> MFMA GEMM -> embed -> ln_pre
    im2col_split_k<<<(CROWS * DMODEL / 4 + 255) / 256, 256, 0, stream>>>(x, gb);
    cvt_w_k<<<(DMODEL * DMODEL / 4 + 255) / 256, 256, 0, stream>>>(conv1_w, wbuf, DMODEL * DMODEL, DMODEL);
    gemm_mfma_k<<<dim3(DMODEL / 128, (CROWS + 127) / 128), 256, 0, stream>>>(
        gb, wbuf, nullptr, sc, nullptr, CROWS, DMODEL, 2 * DMODEL, 0);
    embed_k<<<(ROWS * DMODEL + 255) / 256, 256, 0, stream>>>(sc, cls, pos, h);
    ln768_k<<<ROWS, 256, 0, stream>>>(h, h, ln_pre_w, ln_pre_b);
    gauss_k<<<(NTOK * NTOK + 255) / 256, 256, 0, stream>>>(add);
    cvt_pT_k<<<(DOUT * DMODEL + 255) / 256, 256, 0, stream>>>(proj, pTs);

    const int GY = (ROWS + 127) / 128;  // 50
    for (int l = 0; l < NLAYER; ++l) {
        ln768_split_k<<<ROWS, 256, 0, stream>>>(h, tb, ln1_w + l * DMODEL, ln1_b + l * DMODEL);
        cvt_w_k<<<(DQKV * DMODEL / 4 + 255) / 256, 256, 0, stream>>>(
            in_proj_w + (size_t)l * DQKV * DMODEL, wbuf, DQKV * DMODEL, DMODEL);
        gemm_mfma_k<<<dim3(DQKV / 128, GY), 256, 0, stream>>>(
            tb, wbuf, in_proj_b + (size_t)l * DQKV, qkv, nullptr, ROWS, DQKV, 2 * DMODEL, 0);
        bool nac = (l == NLAYER - 1);
        attn_scores_k<<<dim3(13, NBH), 256, 0, stream>>>(qkv, sc, nac ? add : nullptr, nac ? DMODEL : 0);
        softmax197_k<<<NBH * NTOK, 64, 0, stream>>>(sc);
        attn_pv_split_k<<<dim3(13, NBH), 256, 0, stream>>>(sc, qkv, tb);
        cvt_w_k<<<(DMODEL * DMODEL / 4 + 255) / 256, 256, 0, stream>>>(
            out_proj_w + (size_t)l * DMODEL * DMODEL, wbuf, DMODEL * DMODEL, DMODEL);
        gemm_mfma_k<<<dim3(DMODEL / 128, GY), 256, 0, stream>>>(
            tb, wbuf, out_proj_b + (size_t)l * DMODEL, h, nullptr, ROWS, DMODEL, 2 * DMODEL, 2);
        ln768_split_k<<<ROWS, 256, 0, stream>>>(h, tb, ln2_w + l * DMODEL, ln2_b + l * DMODEL);
        cvt_w_k<<<(DFF * DMODEL / 4 + 255) / 256, 256, 0, stream>>>(
            fc_w + (size_t)l * DFF * DMODEL, wbuf, DFF * DMODEL, DMODEL);
        gemm_mfma_k<<<dim3(DFF / 128, GY), 256, 0, stream>>>(
            tb, wbuf, fc_b + (size_t)l * DFF, nullptr, gb, ROWS, DFF, 2 * DMODEL, 1);
        cvt_w_k<<<(DMODEL * DFF / 4 + 255) / 256, 256, 0, stream>>>(
            cproj_w + (size_t)l * DMODEL * DFF, wbuf, DMODEL * DFF, DFF);
        gemm_mfma_k<<<dim3(DMODEL / 128, GY), 256, 0, stream>>>(
            gb, wbuf, cproj_b + (size_t)l * DMODEL, h, nullptr, ROWS, DMODEL, 2 * DFF, 2);
    }

    ln768_split_k<<<ROWS, 256, 0, stream>>>(h, tb, ln_post_w, ln_post_b);
    gemm_mfma_k<<<dim3(DOUT / 128, GY), 256, 0, stream>>>(
        tb, pTs, nullptr, out, nullptr, ROWS, DOUT, 2 * DMODEL, 0);
}

// Round 3
// 5486.225 us; speedup vs baseline: 3.3716x; 1.4771x over previous
//
#include <hip/hip_runtime.h>
#include <hip/hip_bf16.h>
#include <math.h>

// ---------------- problem constants ----------------
#define BATCH 32
#define NTOK  197
#define NPATCH 196
#define DMODEL 768
#define NLAYER 12
#define NHEAD 12
#define HDIM  64
#define ROWS  (BATCH*NTOK)     // 6304
#define CROWS (BATCH*NPATCH)   // 6272
#define DFF   3072
#define DQKV  2304
#define DOUT  512
#define NBH   (BATCH*NHEAD)

// workspace layout (float units)
#define WS_H    ((size_t)0)                               // h: ROWS*768 f32
#define WS_QKV  ((size_t)ROWS*DMODEL)                     // qkv: ROWS*2304 f32 (also conv out f32)
#define WS_SC   (WS_QKV + (size_t)ROWS*DQKV)              // scores f32 NBH*197*197  (aliases gb)
#define WS_TB   (WS_SC + (size_t)NBH*NTOK*NTOK)           // tb: ROWS*768 bf16 (also im2col)
#define WS_WB   (WS_TB + (size_t)ROWS*DMODEL/2)           // wbuf: max 2.36M bf16
#define WS_PTS  (WS_WB + (size_t)DFF*DMODEL/2)            // pTs: 512*768 bf16
#define WS_ADD  (WS_PTS + (size_t)DOUT*DMODEL/2)          // addition 197*197 f32

typedef unsigned short ushort_t;
typedef __attribute__((ext_vector_type(8))) short bf16x8;
typedef __attribute__((ext_vector_type(4))) float f32x4;

__device__ inline ushort_t bf16rn(float x) {
    uint32_t u = __builtin_bit_cast(uint32_t, x);
    uint32_t r = (u + 0x7FFFu + ((u >> 16) & 1u)) >> 16;
    return (ushort_t)r;
}

// ---------------- small kernels ----------------

// x [32,3,224,224] -> tb bf16 [6272][768]
__global__ void im2col_bf16_k(const float* __restrict__ x, ushort_t* __restrict__ out) {
    int idx = blockIdx.x * 256 + threadIdx.x;
    if (idx >= CROWS * DMODEL / 4) return;
    int r  = idx / (DMODEL / 4);
    int k4 = (idx - r * (DMODEL / 4)) * 4;
    int b = r / NPATCH, p = r - b * NPATCH;
    int py = p / 14, px = p - py * 14;
    int c = k4 >> 8, rem = k4 & 255, i = rem >> 4, j = rem & 15;
    const float* xp = x + (((size_t)(b * 3 + c) * 224) + py * 16 + i) * 224 + px * 16 + j;
    float4 v = *(const float4*)xp;
    ushort4 hv = {bf16rn(v.x), bf16rn(v.y), bf16rn(v.z), bf16rn(v.w)};
    *(ushort4*)(out + (size_t)r * DMODEL + k4) = hv;
}

// W fp32 [N,K] -> bf16 [N][K]
__global__ void cvt_w_k(const float* __restrict__ W, ushort_t* __restrict__ out, int NK) {
    int idx = (blockIdx.x * 256 + threadIdx.x) * 4;
    if (idx >= NK) return;
    float4 v = *(const float4*)(W + idx);
    ushort4 hv = {bf16rn(v.x), bf16rn(v.y), bf16rn(v.z), bf16rn(v.w)};
    *(ushort4*)(out + idx) = hv;
}

// proj [768][512] -> pTs bf16 [512][768]
__global__ void cvt_pT_k(const float* __restrict__ proj, ushort_t* __restrict__ out) {
    int idx = blockIdx.x * 256 + threadIdx.x;
    if (idx >= DOUT * DMODEL) return;
    int n = idx / DMODEL, k = idx - n * DMODEL;
    out[(size_t)n * DMODEL + k] = bf16rn(proj[(size_t)k * DOUT + n]);
}

__global__ void embed_k(const float* __restrict__ conv, const float* __restrict__ cls,
                        const float* __restrict__ pos, float* __restrict__ h) {
    int idx = blockIdx.x * 256 + threadIdx.x;
    if (idx >= ROWS * DMODEL) return;
    int r = idx / DMODEL, d = idx - r * DMODEL;
    int b = r / NTOK, tok = r - b * NTOK;
    float v = (tok == 0) ? cls[d] : conv[((size_t)(b * NPATCH + tok - 1)) * DMODEL + d];
    h[idx] = v + pos[(size_t)tok * DMODEL + d];
}

__global__ void gauss_k(float* __restrict__ add) {
    int idx = blockIdx.x * 256 + threadIdx.x;
    if (idx >= NTOK * NTOK) return;
    int i = idx / NTOK, j = idx - i * NTOK;
    float v = 0.f;
    if (i > 0 && j > 0) {
        int p = i - 1, q = j - 1;
        int di = q / 14 - p / 14;
        int dj = q % 14 - p % 14;
        v = expf(-(float)(di * di + dj * dj) * 0.02f);
    }
    add[idx] = v;
}

// LayerNorm fp32 in-place (ln_pre)
__global__ __launch_bounds__(256) void ln768_k(const float* __restrict__ in, float* __restrict__ out,
                                               const float* __restrict__ w, const float* __restrict__ b) {
    int row = blockIdx.x, tid = threadIdx.x;
    const float* x = in + (size_t)row * DMODEL;
    float v0 = x[tid], v1 = x[tid + 256], v2 = x[tid + 512];
    float s = v0 + v1 + v2;
    float s2 = v0 * v0 + v1 * v1 + v2 * v2;
    for (int o = 32; o > 0; o >>= 1) { s += __shfl_down(s, o); s2 += __shfl_down(s2, o); }
    __shared__ float red[8];
    int wid = tid >> 6;
    if ((tid & 63) == 0) { red[wid] = s; red[4 + wid] = s2; }
    __syncthreads();
    s  = red[0] + red[1] + red[2] + red[3];
    s2 = red[4] + red[5] + red[6] + red[7];
    float mean = s * (1.0f / 768.0f);
    float var  = s2 * (1.0f / 768.0f) - mean * mean;
    float rinv = rsqrtf(var + 1e-5f);
    float* o_ = out + (size_t)row * DMODEL;
    o_[tid]       = (v0 - mean) * rinv * w[tid]       + b[tid];
    o_[tid + 256] = (v1 - mean) * rinv * w[tid + 256] + b[tid + 256];
    o_[tid + 512] = (v2 - mean) * rinv * w[tid + 512] + b[tid + 512];
}

// LayerNorm fp32 -> bf16 [row][768]
__global__ __launch_bounds__(256) void ln768_bf16_k(const float* __restrict__ in, ushort_t* __restrict__ out,
                                                    const float* __restrict__ w, const float* __restrict__ b) {
    int row = blockIdx.x, tid = threadIdx.x;
    const float* x = in + (size_t)row * DMODEL;
    float v0 = x[tid], v1 = x[tid + 256], v2 = x[tid + 512];
    float s = v0 + v1 + v2;
    float s2 = v0 * v0 + v1 * v1 + v2 * v2;
    for (int o = 32; o > 0; o >>= 1) { s += __shfl_down(s, o); s2 += __shfl_down(s2, o); }
    __shared__ float red[8];
    int wid = tid >> 6;
    if ((tid & 63) == 0) { red[wid] = s; red[4 + wid] = s2; }
    __syncthreads();
    s  = red[0] + red[1] + red[2] + red[3];
    s2 = red[4] + red[5] + red[6] + red[7];
    float mean = s * (1.0f / 768.0f);
    float var  = s2 * (1.0f / 768.0f) - mean * mean;
    float rinv = rsqrtf(var + 1e-5f);
    ushort_t* o_ = out + (size_t)row * DMODEL;
    o_[tid]       = bf16rn((v0 - mean) * rinv * w[tid]       + b[tid]);
    o_[tid + 256] = bf16rn((v1 - mean) * rinv * w[tid + 256] + b[tid + 256]);
    o_[tid + 512] = bf16rn((v2 - mean) * rinv * w[tid + 512] + b[tid + 512]);
}

// ---------------- MFMA GEMM:  C[M,N] (+)= A[M,K]bf16 @ W[N,K]bf16^T ----------------
// mode 0: C = r + bias
// mode 1: OS = bf16(quick_gelu(r + bias))
// mode 2: C += r + bias
// mode 3: atomicAdd(C, r (+bias if blockIdx.z==0))   [split-K over gridDim.z]
__global__ __launch_bounds__(256) void gemm_mfma_k(
    const ushort_t* __restrict__ A, const ushort_t* __restrict__ W,
    const float* __restrict__ bias, float* __restrict__ C, ushort_t* __restrict__ OS,
    int M, int N, int K, int mode)
{
    __shared__ ushort_t As[128][32];
    __shared__ ushort_t Bs[128][32];
    int tid = threadIdx.x;
    int lane = tid & 63;
    int wave = tid >> 6;
    int wm = wave >> 1, wn = wave & 1;
    int m0 = blockIdx.y * 128, n0 = blockIdx.x * 128;

    int klen = K / gridDim.z;
    int kbeg = blockIdx.z * klen;
    int kend = kbeg + klen;

    f32x4 acc[4][4];
    #pragma unroll
    for (int i = 0; i < 4; ++i)
        #pragma unroll
        for (int j = 0; j < 4; ++j)
            acc[i][j] = (f32x4){0.f, 0.f, 0.f, 0.f};

    int srow = tid >> 2;                                  // LDS row this lane fills
    int skq  = (((tid & 3) ^ ((tid >> 3) & 3)) * 8);      // pre-swizzled source slot (T2/m173)
    int ar0 = m0 + srow;      if (ar0 > M - 1) ar0 = M - 1;
    int ar1 = m0 + srow + 64; if (ar1 > M - 1) ar1 = M - 1;
    const ushort_t* Ap0 = A + (size_t)ar0 * K + kbeg + skq;
    const ushort_t* Ap1 = A + (size_t)ar1 * K + kbeg + skq;
    const ushort_t* Wp0 = W + (size_t)(n0 + srow) * K + kbeg + skq;
    const ushort_t* Wp1 = W + (size_t)(n0 + srow + 64) * K + kbeg + skq;
    char* ldsA0 = (char*)&As[0][0] + tid * 16;
    char* ldsA1 = ldsA0 + 4096;
    char* ldsB0 = (char*)&Bs[0][0] + tid * 16;
    char* ldsB1 = ldsB0 + 4096;

    int fr = lane & 15, fq = lane >> 4;
    int rsl = (fq ^ ((fr >> 1) & 3)) * 8;                 // swizzled read slot

    for (int k0 = 0; k0 < klen; k0 += 32) {
        __builtin_amdgcn_global_load_lds((const __attribute__((address_space(1))) void*)(Ap0 + k0),
                                         (__attribute__((address_space(3))) void*)ldsA0, 16, 0, 0);
        __builtin_amdgcn_global_load_lds((const __attribute__((address_space(1))) void*)(Ap1 + k0),
                                         (__attribute__((address_space(3))) void*)ldsA1, 16, 0, 0);
        __builtin_amdgcn_global_load_lds((const __attribute__((address_space(1))) void*)(Wp0 + k0),
                                         (__attribute__((address_space(3))) void*)ldsB0, 16, 0, 0);
        __builtin_amdgcn_global_load_lds((const __attribute__((address_space(1))) void*)(Wp1 + k0),
                                         (__attribute__((address_space(3))) void*)ldsB1, 16, 0, 0);
        __syncthreads();

        bf16x8 a[4], b[4];
        #pragma unroll
        for (int fm = 0; fm < 4; ++fm)
            a[fm] = *(const bf16x8*)&As[wm * 64 + fm * 16 + fr][rsl];
        #pragma unroll
        for (int fn = 0; fn < 4; ++fn)
            b[fn] = *(const bf16x8*)&Bs[wn * 64 + fn * 16 + fr][rsl];
        #pragma unroll
        for (int fm = 0; fm < 4; ++fm)
            #pragma unroll
            for (int fn = 0; fn < 4; ++fn)
                acc[fm][fn] = __builtin_amdgcn_mfma_f32_16x16x32_bf16(a[fm], b[fn], acc[fm][fn], 0, 0, 0);
        __syncthreads();
    }

    // epilogue: D col = lane&15 (fr), row = fq*4 + j
    #pragma unroll
    for (int fn = 0; fn < 4; ++fn) {
        int ccol = n0 + wn * 64 + fn * 16 + fr;
        float bv = bias ? bias[ccol] : 0.f;
        if (mode == 3 && blockIdx.z != 0) bv = 0.f;
        #pragma unroll
        for (int fm = 0; fm < 4; ++fm) {
            int crow0 = m0 + wm * 64 + fm * 16 + fq * 4;
            #pragma unroll
            for (int j = 0; j < 4; ++j) {
                int row = crow0 + j;
                if (row < M) {
                    float v = acc[fm][fn][j] + bv;
                    if (mode == 0) {
                        C[(size_t)row * N + ccol] = v;
                    } else if (mode == 2) {
                        C[(size_t)row * N + ccol] += v;
                    } else if (mode == 3) {
                        atomicAdd(&C[(size_t)row * N + ccol], v);
                    } else {
                        v = v / (1.0f + expf(-1.702f * v));
                        OS[(size_t)row * N + ccol] = bf16rn(v);
                    }
                }
            }
        }
    }
}

// ---------------- attention (fp32 VALU) ----------------
__global__ __launch_bounds__(256) void attn_scores_k(
    const float* __restrict__ qkv, float* __restrict__ S,
    const float* __restrict__ addition, int qoff)
{
    int bh = blockIdx.y;
    int b = bh / NHEAD, hh = bh - b * NHEAD;
    int i0 = blockIdx.x * 16;
    int tid = threadIdx.x;
    int tj = tid & 15, ti = tid >> 4;
    __shared__ float Qs[16][64];
    __shared__ float Ks[16][68];
    int lrow = tid >> 4, d4 = (tid & 15) * 4;
    {
        int qrow = i0 + lrow;
        float4 qv = {0,0,0,0};
        if (qrow < NTOK) qv = *(const float4*)(qkv + ((size_t)(b * NTOK + qrow)) * DQKV + qoff + hh * HDIM + d4);
        *(float4*)&Qs[lrow][d4] = qv;
    }
    float* Sbase = S + (size_t)bh * NTOK * NTOK;
    for (int jt = 0; jt < 13; ++jt) {
        int j0 = jt * 16;
        int krow = j0 + lrow;
        float4 kv = {0,0,0,0};
        if (krow < NTOK) kv = *(const float4*)(qkv + ((size_t)(b * NTOK + krow)) * DQKV + DMODEL + hh * HDIM + d4);
        __syncthreads();
        *(float4*)&Ks[lrow][d4] = kv;
        __syncthreads();
        float acc = 0.f;
        #pragma unroll
        for (int dq = 0; dq < 16; ++dq) {
            float4 q4 = *(const float4*)&Qs[ti][dq * 4];
            float4 k4 = *(const float4*)&Ks[tj][dq * 4];
            acc += q4.x * k4.x + q4.y * k4.y + q4.z * k4.z + q4.w * k4.w;
        }
        int irow = i0 + ti, jcol = j0 + tj;
        if (irow < NTOK && jcol < NTOK) {
            float v = acc * 0.125f;
            if (addition) v += addition[irow * NTOK + jcol];
            Sbase[(size_t)irow * NTOK + jcol] = v;
        }
    }
}

__global__ __launch_bounds__(64) void softmax197_k(float* __restrict__ S) {
    size_t row = blockIdx.x;
    float* p = S + row * NTOK;
    int lane = threadIdx.x;
    float v[4], e[4];
    float mx = -1e30f;
    #pragma unroll
    for (int c = 0; c < 4; ++c) {
        int j = lane + c * 64;
        v[c] = (j < NTOK) ? p[j] : -1e30f;
        mx = fmaxf(mx, v[c]);
    }
    for (int o = 32; o > 0; o >>= 1) mx = fmaxf(mx, __shfl_xor(mx, o));
    float sum = 0.f;
    #pragma unroll
    for (int c = 0; c < 4; ++c) { e[c] = expf(v[c] - mx); sum += e[c]; }
    for (int o = 32; o > 0; o >>= 1) sum += __shfl_xor(sum, o);
    float inv = 1.0f / sum;
    #pragma unroll
    for (int c = 0; c < 4; ++c) {
        int j = lane + c * 64;
        if (j < NTOK) p[j] = e[c] * inv;
    }
}

// PV -> bf16 into tb [row][768]
__global__ __launch_bounds__(256) void attn_pv_bf16_k(
    const float* __restrict__ S, const float* __restrict__ qkv, ushort_t* __restrict__ out)
{
    int bh = blockIdx.y;
    int b = bh / NHEAD, hh = bh - b * NHEAD;
    int i0 = blockIdx.x * 16;
    int tid = threadIdx.x;
    int td = tid & 15, ti = tid >> 4;
    __shared__ float Vs[16][64];
    __shared__ float Ps[16][16];
    float4 acc = {0,0,0,0};
    const float* Sbase = S + (size_t)bh * NTOK * NTOK;
    int lrow = tid >> 4, d4 = (tid & 15) * 4;
    for (int jt = 0; jt < 13; ++jt) {
        int j0 = jt * 16;
        float4 vv = {0,0,0,0};
        int vrow = j0 + lrow;
        if (vrow < NTOK) vv = *(const float4*)(qkv + ((size_t)(b * NTOK + vrow)) * DQKV + 2 * DMODEL + hh * HDIM + d4);
        float pv = 0.f;
        int irow = i0 + ti, jcol = j0 + td;
        if (irow < NTOK && jcol < NTOK) pv = Sbase[(size_t)irow * NTOK + jcol];
        __syncthreads();
        *(float4*)&Vs[lrow][d4] = vv;
        Ps[ti][td] = pv;
        __syncthreads();
        #pragma unroll
        for (int jj = 0; jj < 16; ++jj) {
            float pp = Ps[ti][jj];
            float4 vr = *(const float4*)&Vs[jj][td * 4];
            acc.x = fmaf(pp, vr.x, acc.x);
            acc.y = fmaf(pp, vr.y, acc.y);
            acc.z = fmaf(pp, vr.z, acc.z);
            acc.w = fmaf(pp, vr.w, acc.w);
        }
    }
    int irow = i0 + ti;
    if (irow < NTOK) {
        ushort4 hv = {bf16rn(acc.x), bf16rn(acc.y), bf16rn(acc.z), bf16rn(acc.w)};
        *(ushort4*)(out + ((size_t)(b * NTOK + irow)) * DMODEL + hh * HDIM + td * 4) = hv;
    }
}

// ---------------- launch ----------------
extern "C" void kernel_launch(void* const* d_in, const int* in_sizes, int n_in,
                              void* d_out, int out_size, void* d_ws, size_t ws_size,
                              hipStream_t stream) {
    const float* x        = (const float*)d_in[0];
    const float* conv1_w  = (const float*)d_in[1];
    const float* cls      = (const float*)d_in[2];
    const float* pos      = (const float*)d_in[3];
    const float* ln_pre_w = (const float*)d_in[4];
    const float* ln_pre_b = (const float*)d_in[5];
    const float* in_proj_w  = (const float*)d_in[6];
    const float* in_proj_b  = (const float*)d_in[7];
    const float* out_proj_w = (const float*)d_in[8];
    const float* out_proj_b = (const float*)d_in[9];
    const float* ln1_w = (const float*)d_in[10];
    const float* ln1_b = (const float*)d_in[11];
    const float* ln2_w = (const float*)d_in[12];
    const float* ln2_b = (const float*)d_in[13];
    const float* fc_w  = (const float*)d_in[14];
    const float* fc_b  = (const float*)d_in[15];
    const float* cproj_w = (const float*)d_in[16];
    const float* cproj_b = (const float*)d_in[17];
    const float* ln_post_w = (const float*)d_in[18];
    const float* ln_post_b = (const float*)d_in[19];
    const float* proj = (const float*)d_in[20];
    float* out = (float*)d_out;

    float* ws   = (float*)d_ws;
    float* h    = ws + WS_H;
    float* qkv  = ws + WS_QKV;
    float* sc   = ws + WS_SC;
    ushort_t* gb   = (ushort_t*)(ws + WS_SC);   // aliases scores (disjoint in time)
    ushort_t* tb   = (ushort_t*)(ws + WS_TB);
    ushort_t* wbuf = (ushort_t*)(ws + WS_WB);
    ushort_t* pTs  = (ushort_t*)(ws + WS_PTS);
    float* add  = ws + WS_ADD;

    // patch embedding: im2col(bf16) -> MFMA GEMM (out f32 into qkv region) -> embed -> ln_pre
    im2col_bf16_k<<<(CROWS * DMODEL / 4 + 255) / 256, 256, 0, stream>>>(x, tb);
    cvt_w_k<<<(DMODEL * DMODEL / 4 + 255) / 256, 256, 0, stream>>>(conv1_w, wbuf, DMODEL * DMODEL);
    gemm_mfma_k<<<dim3(DMODEL / 128, (CROWS + 127) / 128), 256, 0, stream>>>(
        tb, wbuf, nullptr, qkv, nullptr, CROWS, DMODEL, DMODEL, 0);
    embed_k<<<(ROWS * DMODEL + 255) / 256, 256, 0, stream>>>(qkv, cls, pos, h);
    ln768_k<<<ROWS, 256, 0, stream>>>(h, h, ln_pre_w, ln_pre_b);
    gauss_k<<<(NTOK * NTOK + 255) / 256, 256, 0, stream>>>(add);
    cvt_pT_k<<<(DOUT * DMODEL + 255) / 256, 256, 0, stream>>>(proj, pTs);

    const int GY = (ROWS + 127) / 128;  // 50
    for (int l = 0; l < NLAYER; ++l) {
        ln768_bf16_k<<<ROWS, 256, 0, stream>>>(h, tb, ln1_w + l * DMODEL, ln1_b + l * DMODEL);
        cvt_w_k<<<(DQKV * DMODEL / 4 + 255) / 256, 256, 0, stream>>>(
            in_proj_w + (size_t)l * DQKV * DMODEL, wbuf, DQKV * DMODEL);
        gemm_mfma_k<<<dim3(DQKV / 128, GY), 256, 0, stream>>>(
            tb, wbuf, in_proj_b + (size_t)l * DQKV, qkv, nullptr, ROWS, DQKV, DMODEL, 0);
        bool nac = (l == NLAYER - 1);
        attn_scores_k<<<dim3(13, NBH), 256, 0, stream>>>(qkv, sc, nac ? add : nullptr, nac ? DMODEL : 0);
        softmax197_k<<<NBH * NTOK, 64, 0, stream>>>(sc);
        attn_pv_bf16_k<<<dim3(13, NBH), 256, 0, stream>>>(sc, qkv, tb);
        cvt_w_k<<<(DMODEL * DMODEL / 4 + 255) / 256, 256, 0, stream>>>(
            out_proj_w + (size_t)l * DMODEL * DMODEL, wbuf, DMODEL * DMODEL);
        gemm_mfma_k<<<dim3(DMODEL / 128, GY, 2), 256, 0, stream>>>(
            tb, wbuf, out_proj_b + (size_t)l * DMODEL, h, nullptr, ROWS, DMODEL, DMODEL, 3);
        ln768_bf16_k<<<ROWS, 256, 0, stream>>>(h, tb, ln2_w + l * DMODEL, ln2_b + l * DMODEL);
        cvt_w_k<<<(DFF * DMODEL / 4 + 255) / 256, 256, 0, stream>>>(
            fc_w + (size_t)l * DFF * DMODEL, wbuf, DFF * DMODEL);
        gemm_mfma_k<<<dim3(DFF / 128, GY), 256, 0, stream>>>(
            tb, wbuf, fc_b + (size_t)l * DFF, nullptr, gb, ROWS, DFF, DMODEL, 1);
        cvt_w_k<<<(DMODEL * DFF / 4 + 255) / 256, 256, 0, stream>>>(
            cproj_w + (size_t)l * DMODEL * DFF, wbuf, DMODEL * DFF);
        gemm_mfma_k<<<dim3(DMODEL / 128, GY, 2), 256, 0, stream>>>(
            gb, wbuf, cproj_b + (size_t)l * DMODEL, h, nullptr, ROWS, DMODEL, DFF, 3);
    }

    ln768_bf16_k<<<ROWS, 256, 0, stream>>>(h, tb, ln_post_w, ln_post_b);
    gemm_mfma_k<<<dim3(DOUT / 128, GY), 256, 0, stream>>>(
        tb, pTs, nullptr, out, nullptr, ROWS, DOUT, DMODEL, 0);
}

// Round 4
// 3866.697 us; speedup vs baseline: 4.7838x; 1.4188x over previous
//
#include <hip/hip_runtime.h>
#include <hip/hip_bf16.h>
#include <math.h>

// ---------------- problem constants ----------------
#define BATCH 32
#define NTOK  197
#define NPATCH 196
#define DMODEL 768
#define NLAYER 12
#define NHEAD 12
#define HDIM  64
#define ROWS  (BATCH*NTOK)     // 6304
#define CROWS (BATCH*NPATCH)   // 6272
#define DFF   3072
#define DQKV  2304
#define DOUT  512
#define NBH   (BATCH*NHEAD)

// workspace layout (float units)
#define WS_H    ((size_t)0)                               // h: ROWS*768 f32
#define WS_QKV  ((size_t)ROWS*DMODEL)                     // qkv: ROWS*2304 f32 (also conv out f32)
#define WS_SC   (WS_QKV + (size_t)ROWS*DQKV)              // gb: ROWS*3072 bf16 (mlp) ; also im2col f32 era
#define WS_TB   (WS_SC + (size_t)NBH*NTOK*NTOK)           // tb: ROWS*768 bf16 (also im2col)
#define WS_WB   (WS_TB + (size_t)ROWS*DMODEL/2)           // wbuf: max 2.36M bf16
#define WS_PTS  (WS_WB + (size_t)DFF*DMODEL/2)            // pTs: 512*768 bf16
#define WS_ADD  (WS_PTS + (size_t)DOUT*DMODEL/2)          // addition 197*197 f32

typedef unsigned short ushort_t;
typedef __attribute__((ext_vector_type(8))) short bf16x8;
typedef __attribute__((ext_vector_type(4))) float f32x4;

__device__ inline ushort_t bf16rn(float x) {
    uint32_t u = __builtin_bit_cast(uint32_t, x);
    uint32_t r = (u + 0x7FFFu + ((u >> 16) & 1u)) >> 16;
    return (ushort_t)r;
}

// ---------------- small kernels ----------------

// x [32,3,224,224] -> tb bf16 [6272][768]
__global__ void im2col_bf16_k(const float* __restrict__ x, ushort_t* __restrict__ out) {
    int idx = blockIdx.x * 256 + threadIdx.x;
    if (idx >= CROWS * DMODEL / 4) return;
    int r  = idx / (DMODEL / 4);
    int k4 = (idx - r * (DMODEL / 4)) * 4;
    int b = r / NPATCH, p = r - b * NPATCH;
    int py = p / 14, px = p - py * 14;
    int c = k4 >> 8, rem = k4 & 255, i = rem >> 4, j = rem & 15;
    const float* xp = x + (((size_t)(b * 3 + c) * 224) + py * 16 + i) * 224 + px * 16 + j;
    float4 v = *(const float4*)xp;
    ushort4 hv = {bf16rn(v.x), bf16rn(v.y), bf16rn(v.z), bf16rn(v.w)};
    *(ushort4*)(out + (size_t)r * DMODEL + k4) = hv;
}

// W fp32 [N,K] -> bf16 [N][K]
__global__ void cvt_w_k(const float* __restrict__ W, ushort_t* __restrict__ out, int NK) {
    int idx = (blockIdx.x * 256 + threadIdx.x) * 4;
    if (idx >= NK) return;
    float4 v = *(const float4*)(W + idx);
    ushort4 hv = {bf16rn(v.x), bf16rn(v.y), bf16rn(v.z), bf16rn(v.w)};
    *(ushort4*)(out + idx) = hv;
}

// proj [768][512] -> pTs bf16 [512][768]
__global__ void cvt_pT_k(const float* __restrict__ proj, ushort_t* __restrict__ out) {
    int idx = blockIdx.x * 256 + threadIdx.x;
    if (idx >= DOUT * DMODEL) return;
    int n = idx / DMODEL, k = idx - n * DMODEL;
    out[(size_t)n * DMODEL + k] = bf16rn(proj[(size_t)k * DOUT + n]);
}

__global__ void embed_k(const float* __restrict__ conv, const float* __restrict__ cls,
                        const float* __restrict__ pos, float* __restrict__ h) {
    int idx = blockIdx.x * 256 + threadIdx.x;
    if (idx >= ROWS * DMODEL) return;
    int r = idx / DMODEL, d = idx - r * DMODEL;
    int b = r / NTOK, tok = r - b * NTOK;
    float v = (tok == 0) ? cls[d] : conv[((size_t)(b * NPATCH + tok - 1)) * DMODEL + d];
    h[idx] = v + pos[(size_t)tok * DMODEL + d];
}

__global__ void gauss_k(float* __restrict__ add) {
    int idx = blockIdx.x * 256 + threadIdx.x;
    if (idx >= NTOK * NTOK) return;
    int i = idx / NTOK, j = idx - i * NTOK;
    float v = 0.f;
    if (i > 0 && j > 0) {
        int p = i - 1, q = j - 1;
        int di = q / 14 - p / 14;
        int dj = q % 14 - p % 14;
        v = expf(-(float)(di * di + dj * dj) * 0.02f);
    }
    add[idx] = v;
}

// LayerNorm fp32 in-place (ln_pre)
__global__ __launch_bounds__(256) void ln768_k(const float* __restrict__ in, float* __restrict__ out,
                                               const float* __restrict__ w, const float* __restrict__ b) {
    int row = blockIdx.x, tid = threadIdx.x;
    const float* x = in + (size_t)row * DMODEL;
    float v0 = x[tid], v1 = x[tid + 256], v2 = x[tid + 512];
    float s = v0 + v1 + v2;
    float s2 = v0 * v0 + v1 * v1 + v2 * v2;
    for (int o = 32; o > 0; o >>= 1) { s += __shfl_down(s, o); s2 += __shfl_down(s2, o); }
    __shared__ float red[8];
    int wid = tid >> 6;
    if ((tid & 63) == 0) { red[wid] = s; red[4 + wid] = s2; }
    __syncthreads();
    s  = red[0] + red[1] + red[2] + red[3];
    s2 = red[4] + red[5] + red[6] + red[7];
    float mean = s * (1.0f / 768.0f);
    float var  = s2 * (1.0f / 768.0f) - mean * mean;
    float rinv = rsqrtf(var + 1e-5f);
    float* o_ = out + (size_t)row * DMODEL;
    o_[tid]       = (v0 - mean) * rinv * w[tid]       + b[tid];
    o_[tid + 256] = (v1 - mean) * rinv * w[tid + 256] + b[tid + 256];
    o_[tid + 512] = (v2 - mean) * rinv * w[tid + 512] + b[tid + 512];
}

// LayerNorm fp32 -> bf16 [row][768]
__global__ __launch_bounds__(256) void ln768_bf16_k(const float* __restrict__ in, ushort_t* __restrict__ out,
                                                    const float* __restrict__ w, const float* __restrict__ b) {
    int row = blockIdx.x, tid = threadIdx.x;
    const float* x = in + (size_t)row * DMODEL;
    float v0 = x[tid], v1 = x[tid + 256], v2 = x[tid + 512];
    float s = v0 + v1 + v2;
    float s2 = v0 * v0 + v1 * v1 + v2 * v2;
    for (int o = 32; o > 0; o >>= 1) { s += __shfl_down(s, o); s2 += __shfl_down(s2, o); }
    __shared__ float red[8];
    int wid = tid >> 6;
    if ((tid & 63) == 0) { red[wid] = s; red[4 + wid] = s2; }
    __syncthreads();
    s  = red[0] + red[1] + red[2] + red[3];
    s2 = red[4] + red[5] + red[6] + red[7];
    float mean = s * (1.0f / 768.0f);
    float var  = s2 * (1.0f / 768.0f) - mean * mean;
    float rinv = rsqrtf(var + 1e-5f);
    ushort_t* o_ = out + (size_t)row * DMODEL;
    o_[tid]       = bf16rn((v0 - mean) * rinv * w[tid]       + b[tid]);
    o_[tid + 256] = bf16rn((v1 - mean) * rinv * w[tid + 256] + b[tid + 256]);
    o_[tid + 512] = bf16rn((v2 - mean) * rinv * w[tid + 512] + b[tid + 512]);
}

// ---------------- MFMA GEMM:  C[M,N] (+)= A[M,K]bf16 @ W[N,K]bf16^T ----------------
// mode 0: C = r + bias
// mode 1: OS = bf16(quick_gelu(r + bias))
// mode 2: C += r + bias
// mode 3: atomicAdd(C, r (+bias if blockIdx.z==0))   [split-K over gridDim.z]
__global__ __launch_bounds__(256) void gemm_mfma_k(
    const ushort_t* __restrict__ A, const ushort_t* __restrict__ W,
    const float* __restrict__ bias, float* __restrict__ C, ushort_t* __restrict__ OS,
    int M, int N, int K, int mode)
{
    __shared__ ushort_t As[128][32];
    __shared__ ushort_t Bs[128][32];
    int tid = threadIdx.x;
    int lane = tid & 63;
    int wave = tid >> 6;
    int wm = wave >> 1, wn = wave & 1;
    int m0 = blockIdx.y * 128, n0 = blockIdx.x * 128;

    int klen = K / gridDim.z;
    int kbeg = blockIdx.z * klen;

    f32x4 acc[4][4];
    #pragma unroll
    for (int i = 0; i < 4; ++i)
        #pragma unroll
        for (int j = 0; j < 4; ++j)
            acc[i][j] = (f32x4){0.f, 0.f, 0.f, 0.f};

    int srow = tid >> 2;                                  // LDS row this lane fills
    int skq  = (((tid & 3) ^ ((tid >> 3) & 3)) * 8);      // pre-swizzled source slot
    int ar0 = m0 + srow;      if (ar0 > M - 1) ar0 = M - 1;
    int ar1 = m0 + srow + 64; if (ar1 > M - 1) ar1 = M - 1;
    const ushort_t* Ap0 = A + (size_t)ar0 * K + kbeg + skq;
    const ushort_t* Ap1 = A + (size_t)ar1 * K + kbeg + skq;
    const ushort_t* Wp0 = W + (size_t)(n0 + srow) * K + kbeg + skq;
    const ushort_t* Wp1 = W + (size_t)(n0 + srow + 64) * K + kbeg + skq;
    char* ldsA0 = (char*)&As[0][0] + tid * 16;
    char* ldsA1 = ldsA0 + 4096;
    char* ldsB0 = (char*)&Bs[0][0] + tid * 16;
    char* ldsB1 = ldsB0 + 4096;

    int fr = lane & 15, fq = lane >> 4;
    int rsl = (fq ^ ((fr >> 1) & 3)) * 8;                 // swizzled read slot

    for (int k0 = 0; k0 < klen; k0 += 32) {
        __builtin_amdgcn_global_load_lds((const __attribute__((address_space(1))) void*)(Ap0 + k0),
                                         (__attribute__((address_space(3))) void*)ldsA0, 16, 0, 0);
        __builtin_amdgcn_global_load_lds((const __attribute__((address_space(1))) void*)(Ap1 + k0),
                                         (__attribute__((address_space(3))) void*)ldsA1, 16, 0, 0);
        __builtin_amdgcn_global_load_lds((const __attribute__((address_space(1))) void*)(Wp0 + k0),
                                         (__attribute__((address_space(3))) void*)ldsB0, 16, 0, 0);
        __builtin_amdgcn_global_load_lds((const __attribute__((address_space(1))) void*)(Wp1 + k0),
                                         (__attribute__((address_space(3))) void*)ldsB1, 16, 0, 0);
        __syncthreads();

        bf16x8 a[4], b[4];
        #pragma unroll
        for (int fm = 0; fm < 4; ++fm)
            a[fm] = *(const bf16x8*)&As[wm * 64 + fm * 16 + fr][rsl];
        #pragma unroll
        for (int fn = 0; fn < 4; ++fn)
            b[fn] = *(const bf16x8*)&Bs[wn * 64 + fn * 16 + fr][rsl];
        #pragma unroll
        for (int fm = 0; fm < 4; ++fm)
            #pragma unroll
            for (int fn = 0; fn < 4; ++fn)
                acc[fm][fn] = __builtin_amdgcn_mfma_f32_16x16x32_bf16(a[fm], b[fn], acc[fm][fn], 0, 0, 0);
        __syncthreads();
    }

    // epilogue: D col = lane&15 (fr), row = fq*4 + j
    #pragma unroll
    for (int fn = 0; fn < 4; ++fn) {
        int ccol = n0 + wn * 64 + fn * 16 + fr;
        float bv = bias ? bias[ccol] : 0.f;
        if (mode == 3 && blockIdx.z != 0) bv = 0.f;
        #pragma unroll
        for (int fm = 0; fm < 4; ++fm) {
            int crow0 = m0 + wm * 64 + fm * 16 + fq * 4;
            #pragma unroll
            for (int j = 0; j < 4; ++j) {
                int row = crow0 + j;
                if (row < M) {
                    float v = acc[fm][fn][j] + bv;
                    if (mode == 0) {
                        C[(size_t)row * N + ccol] = v;
                    } else if (mode == 2) {
                        C[(size_t)row * N + ccol] += v;
                    } else if (mode == 3) {
                        atomicAdd(&C[(size_t)row * N + ccol], v);
                    } else {
                        v = v / (1.0f + expf(-1.702f * v));
                        OS[(size_t)row * N + ccol] = bf16rn(v);
                    }
                }
            }
        }
    }
}

// ---------------- fused MFMA flash attention ----------------
// One block per (b,h). Q/K from qkv f32 (qoff selects q or k source), V transposed in LDS.
// out = bf16 attention output [ROWS][768].
__global__ __launch_bounds__(256) void attn_fused_k(
    const float* __restrict__ qkv, ushort_t* __restrict__ out,
    const float* __restrict__ addition, int qoff)
{
    __shared__ ushort_t Ks[208][72];    // 16B-aligned rows
    __shared__ ushort_t Vt[64][232];    // V transposed, 16B-aligned rows
    __shared__ ushort_t Pb[4][16][40];  // per-wave P staging
    int tid = threadIdx.x;
    int bh = blockIdx.x;
    int b = bh / NHEAD, hh = bh - b * NHEAD;
    const float* base = qkv + (size_t)b * NTOK * DQKV + hh * HDIM;

    // stage K [208][72] (zeros for t>=197) and V^T [64][232]
    {
        int tt = tid >> 4, dq = tid & 15;
        #pragma unroll
        for (int pass = 0; pass < 13; ++pass) {
            int t = pass * 16 + tt;      // 0..207
            float4 kv = {0, 0, 0, 0}, vv = {0, 0, 0, 0};
            if (t < NTOK) {
                kv = *(const float4*)(base + (size_t)t * DQKV + DMODEL + dq * 4);
                vv = *(const float4*)(base + (size_t)t * DQKV + 2 * DMODEL + dq * 4);
            }
            ushort4 kh = {bf16rn(kv.x), bf16rn(kv.y), bf16rn(kv.z), bf16rn(kv.w)};
            *(ushort4*)&Ks[t][dq * 4] = kh;
            Vt[dq * 4 + 0][t] = bf16rn(vv.x);
            Vt[dq * 4 + 1][t] = bf16rn(vv.y);
            Vt[dq * 4 + 2][t] = bf16rn(vv.z);
            Vt[dq * 4 + 3][t] = bf16rn(vv.w);
        }
        for (int z = tid; z < 64 * 24; z += 256) Vt[z / 24][208 + z % 24] = 0;
    }
    __syncthreads();

    int lane = tid & 63, wave = tid >> 6;
    int fr = lane & 15, fq = lane >> 4;

    for (int qt = wave; qt < 13; qt += 4) {
        int i0 = qt * 16;
        int qrow = i0 + fr; if (qrow > NTOK - 1) qrow = NTOK - 1;
        const float* qp = base + (size_t)qrow * DQKV + qoff + fq * 8;
        float4 qa = *(const float4*)(qp);
        float4 qb = *(const float4*)(qp + 4);
        float4 qc = *(const float4*)(qp + 32);
        float4 qd = *(const float4*)(qp + 36);
        bf16x8 q0, q1;
        q0[0] = (short)bf16rn(qa.x); q0[1] = (short)bf16rn(qa.y);
        q0[2] = (short)bf16rn(qa.z); q0[3] = (short)bf16rn(qa.w);
        q0[4] = (short)bf16rn(qb.x); q0[5] = (short)bf16rn(qb.y);
        q0[6] = (short)bf16rn(qb.z); q0[7] = (short)bf16rn(qb.w);
        q1[0] = (short)bf16rn(qc.x); q1[1] = (short)bf16rn(qc.y);
        q1[2] = (short)bf16rn(qc.z); q1[3] = (short)bf16rn(qc.w);
        q1[4] = (short)bf16rn(qd.x); q1[5] = (short)bf16rn(qd.y);
        q1[6] = (short)bf16rn(qd.z); q1[7] = (short)bf16rn(qd.w);

        // ---- S = Q K^T : 13 tiles of 16x16, f32 accum. lane: col j=jt*16+fr, row i=i0+fq*4+jj
        f32x4 s[13];
        #pragma unroll
        for (int jt = 0; jt < 13; ++jt) {
            bf16x8 k0 = *(const bf16x8*)&Ks[jt * 16 + fr][fq * 8];
            bf16x8 k1 = *(const bf16x8*)&Ks[jt * 16 + fr][32 + fq * 8];
            f32x4 a = {0.f, 0.f, 0.f, 0.f};
            a = __builtin_amdgcn_mfma_f32_16x16x32_bf16(q0, k0, a, 0, 0, 0);
            a = __builtin_amdgcn_mfma_f32_16x16x32_bf16(q1, k1, a, 0, 0, 0);
            s[jt] = a;
        }

        // ---- softmax over j (197 valid cols)
        int irow[4];
        #pragma unroll
        for (int jj = 0; jj < 4; ++jj) {
            int ir = i0 + fq * 4 + jj;
            irow[jj] = (ir < NTOK) ? ir : (NTOK - 1);
        }
        float m[4] = {-1e30f, -1e30f, -1e30f, -1e30f};
        #pragma unroll
        for (int jt = 0; jt < 13; ++jt) {
            int jcol = jt * 16 + fr;
            #pragma unroll
            for (int jj = 0; jj < 4; ++jj) {
                float v = s[jt][jj] * 0.125f;
                if (addition) v += addition[irow[jj] * NTOK + (jcol < NTOK ? jcol : 0)];
                if (jcol >= NTOK) v = -1e30f;
                s[jt][jj] = v;
                m[jj] = fmaxf(m[jj], v);
            }
        }
        #pragma unroll
        for (int jj = 0; jj < 4; ++jj) {
            m[jj] = fmaxf(m[jj], __shfl_xor(m[jj], 1));
            m[jj] = fmaxf(m[jj], __shfl_xor(m[jj], 2));
            m[jj] = fmaxf(m[jj], __shfl_xor(m[jj], 4));
            m[jj] = fmaxf(m[jj], __shfl_xor(m[jj], 8));
        }
        float sum[4] = {0.f, 0.f, 0.f, 0.f};
        #pragma unroll
        for (int jt = 0; jt < 13; ++jt)
            #pragma unroll
            for (int jj = 0; jj < 4; ++jj) {
                float e = __expf(s[jt][jj] - m[jj]);
                s[jt][jj] = e;
                sum[jj] += e;
            }
        #pragma unroll
        for (int jj = 0; jj < 4; ++jj) {
            sum[jj] += __shfl_xor(sum[jj], 1);
            sum[jj] += __shfl_xor(sum[jj], 2);
            sum[jj] += __shfl_xor(sum[jj], 4);
            sum[jj] += __shfl_xor(sum[jj], 8);
        }
        float inv[4];
        #pragma unroll
        for (int jj = 0; jj < 4; ++jj) inv[jj] = 1.0f / sum[jj];

        // ---- O = P V : P staged bf16 through per-wave LDS (32 j per step)
        f32x4 o4[4];
        #pragma unroll
        for (int dt = 0; dt < 4; ++dt) o4[dt] = (f32x4){0.f, 0.f, 0.f, 0.f};
        for (int st = 0; st < 7; ++st) {
            #pragma unroll
            for (int half = 0; half < 2; ++half) {
                int jt = st * 2 + half;
                #pragma unroll
                for (int jj = 0; jj < 4; ++jj) {
                    ushort_t pv = 0;
                    if (jt < 13) pv = bf16rn(s[jt][jj] * inv[jj]);
                    Pb[wave][fq * 4 + jj][half * 16 + fr] = pv;
                }
            }
            asm volatile("s_waitcnt lgkmcnt(0)" ::: "memory");
            bf16x8 pa = *(const bf16x8*)&Pb[wave][fr][fq * 8];
            #pragma unroll
            for (int dt = 0; dt < 4; ++dt) {
                bf16x8 vf = *(const bf16x8*)&Vt[dt * 16 + fr][st * 32 + fq * 8];
                o4[dt] = __builtin_amdgcn_mfma_f32_16x16x32_bf16(pa, vf, o4[dt], 0, 0, 0);
            }
        }

        // ---- write O bf16: row i, col d = dt*16+fr
        #pragma unroll
        for (int jj = 0; jj < 4; ++jj) {
            int ir = i0 + fq * 4 + jj;
            if (ir < NTOK) {
                ushort_t* op = out + ((size_t)(b * NTOK + ir)) * DMODEL + hh * HDIM + fr;
                #pragma unroll
                for (int dt = 0; dt < 4; ++dt)
                    op[dt * 16] = bf16rn(o4[dt][jj]);
            }
        }
    }
}

// ---------------- launch ----------------
extern "C" void kernel_launch(void* const* d_in, const int* in_sizes, int n_in,
                              void* d_out, int out_size, void* d_ws, size_t ws_size,
                              hipStream_t stream) {
    const float* x        = (const float*)d_in[0];
    const float* conv1_w  = (const float*)d_in[1];
    const float* cls      = (const float*)d_in[2];
    const float* pos      = (const float*)d_in[3];
    const float* ln_pre_w = (const float*)d_in[4];
    const float* ln_pre_b = (const float*)d_in[5];
    const float* in_proj_w  = (const float*)d_in[6];
    const float* in_proj_b  = (const float*)d_in[7];
    const float* out_proj_w = (const float*)d_in[8];
    const float* out_proj_b = (const float*)d_in[9];
    const float* ln1_w = (const float*)d_in[10];
    const float* ln1_b = (const float*)d_in[11];
    const float* ln2_w = (const float*)d_in[12];
    const float* ln2_b = (const float*)d_in[13];
    const float* fc_w  = (const float*)d_in[14];
    const float* fc_b  = (const float*)d_in[15];
    const float* cproj_w = (const float*)d_in[16];
    const float* cproj_b = (const float*)d_in[17];
    const float* ln_post_w = (const float*)d_in[18];
    const float* ln_post_b = (const float*)d_in[19];
    const float* proj = (const float*)d_in[20];
    float* out = (float*)d_out;

    float* ws   = (float*)d_ws;
    float* h    = ws + WS_H;
    float* qkv  = ws + WS_QKV;
    ushort_t* gb   = (ushort_t*)(ws + WS_SC);
    ushort_t* tb   = (ushort_t*)(ws + WS_TB);
    ushort_t* wbuf = (ushort_t*)(ws + WS_WB);
    ushort_t* pTs  = (ushort_t*)(ws + WS_PTS);
    float* add  = ws + WS_ADD;

    // patch embedding: im2col(bf16) -> MFMA GEMM (f32 out into qkv region) -> embed -> ln_pre
    im2col_bf16_k<<<(CROWS * DMODEL / 4 + 255) / 256, 256, 0, stream>>>(x, tb);
    cvt_w_k<<<(DMODEL * DMODEL / 4 + 255) / 256, 256, 0, stream>>>(conv1_w, wbuf, DMODEL * DMODEL);
    gemm_mfma_k<<<dim3(DMODEL / 128, (CROWS + 127) / 128), 256, 0, stream>>>(
        tb, wbuf, nullptr, qkv, nullptr, CROWS, DMODEL, DMODEL, 0);
    embed_k<<<(ROWS * DMODEL + 255) / 256, 256, 0, stream>>>(qkv, cls, pos, h);
    ln768_k<<<ROWS, 256, 0, stream>>>(h, h, ln_pre_w, ln_pre_b);
    gauss_k<<<(NTOK * NTOK + 255) / 256, 256, 0, stream>>>(add);
    cvt_pT_k<<<(DOUT * DMODEL + 255) / 256, 256, 0, stream>>>(proj, pTs);

    const int GY = (ROWS + 127) / 128;  // 50
    for (int l = 0; l < NLAYER; ++l) {
        ln768_bf16_k<<<ROWS, 256, 0, stream>>>(h, tb, ln1_w + l * DMODEL, ln1_b + l * DMODEL);
        cvt_w_k<<<(DQKV * DMODEL / 4 + 255) / 256, 256, 0, stream>>>(
            in_proj_w + (size_t)l * DQKV * DMODEL, wbuf, DQKV * DMODEL);
        gemm_mfma_k<<<dim3(DQKV / 128, GY), 256, 0, stream>>>(
            tb, wbuf, in_proj_b + (size_t)l * DQKV, qkv, nullptr, ROWS, DQKV, DMODEL, 0);
        bool nac = (l == NLAYER - 1);
        attn_fused_k<<<NBH, 256, 0, stream>>>(qkv, tb, nac ? add : nullptr, nac ? DMODEL : 0);
        cvt_w_k<<<(DMODEL * DMODEL / 4 + 255) / 256, 256, 0, stream>>>(
            out_proj_w + (size_t)l * DMODEL * DMODEL, wbuf, DMODEL * DMODEL);
        gemm_mfma_k<<<dim3(DMODEL / 128, GY, 2), 256, 0, stream>>>(
            tb, wbuf, out_proj_b + (size_t)l * DMODEL, h, nullptr, ROWS, DMODEL, DMODEL, 3);
        ln768_bf16_k<<<ROWS, 256, 0, stream>>>(h, tb, ln2_w + l * DMODEL, ln2_b + l * DMODEL);
        cvt_w_k<<<(DFF * DMODEL / 4 + 255) / 256, 256, 0, stream>>>(
            fc_w + (size_t)l * DFF * DMODEL, wbuf, DFF * DMODEL);
        gemm_mfma_k<<<dim3(DFF / 128, GY), 256, 0, stream>>>(
            tb, wbuf, fc_b + (size_t)l * DFF, nullptr, gb, ROWS, DFF, DMODEL, 1);
        cvt_w_k<<<(DMODEL * DFF / 4 + 255) / 256, 256, 0, stream>>>(
            cproj_w + (size_t)l * DMODEL * DFF, wbuf, DMODEL * DFF);
        gemm_mfma_k<<<dim3(DMODEL / 128, GY, 2), 256, 0, stream>>>(
            gb, wbuf, cproj_b + (size_t)l * DMODEL, h, nullptr, ROWS, DMODEL, DFF, 3);
    }

    ln768_bf16_k<<<ROWS, 256, 0, stream>>>(h, tb, ln_post_w, ln_post_b);
    gemm_mfma_k<<<dim3(DOUT / 128, GY), 256, 0, stream>>>(
        tb, pTs, nullptr, out, nullptr, ROWS, DOUT, DMODEL, 0);
}

// Round 5
// 3539.674 us; speedup vs baseline: 5.2258x; 1.0924x over previous
//
#include <hip/hip_runtime.h>
#include <hip/hip_bf16.h>
#include <math.h>

// ---------------- problem constants ----------------
#define BATCH 32
#define NTOK  197
#define NPATCH 196
#define DMODEL 768
#define NLAYER 12
#define NHEAD 12
#define HDIM  64
#define ROWS  (BATCH*NTOK)     // 6304
#define CROWS (BATCH*NPATCH)   // 6272
#define DFF   3072
#define DQKV  2304
#define DOUT  512
#define NBH   (BATCH*NHEAD)

// per-layer weight slab offsets (bf16 elems)
#define WOFF_IN   ((size_t)0)
#define WOFF_OUT  ((size_t)(DQKV*DMODEL))                         // 1769472
#define WOFF_FC   (WOFF_OUT + (size_t)(DMODEL*DMODEL))            // 2359296
#define WOFF_CP   (WOFF_FC + (size_t)(DFF*DMODEL))                // 4718592
#define WTOT      (WOFF_CP + (size_t)(DMODEL*DFF))                // 7077888

// workspace layout (float units)
#define WS_H    ((size_t)0)                                       // h f32: 4841472
#define WS_QKVB (WS_H + (size_t)ROWS*DMODEL)                      // qkv bf16 (ROWS*2304) / conv f32 tmp
#define WS_GB   (WS_QKVB + (size_t)ROWS*DQKV/2)                   // gb bf16 ROWS*3072
#define WS_TB   (WS_GB + (size_t)ROWS*DFF/2)                      // tb bf16 ROWS*768
#define WS_WL   (WS_TB + (size_t)ROWS*DMODEL/2)                   // wl bf16 slab (WTOT)
#define WS_PTS  (WS_WL + WTOT/2)                                  // pTs bf16 512*768
#define WS_ADD  (WS_PTS + (size_t)DOUT*DMODEL/2)                  // addition f32

typedef unsigned short ushort_t;
typedef __attribute__((ext_vector_type(8))) short bf16x8;
typedef __attribute__((ext_vector_type(4))) float f32x4;

__device__ inline ushort_t bf16rn(float x) {
    uint32_t u = __builtin_bit_cast(uint32_t, x);
    uint32_t r = (u + 0x7FFFu + ((u >> 16) & 1u)) >> 16;
    return (ushort_t)r;
}

#define GLL(src, dst) __builtin_amdgcn_global_load_lds( \
    (const __attribute__((address_space(1))) void*)(src), \
    (__attribute__((address_space(3))) void*)(dst), 16, 0, 0)

// ---------------- small kernels ----------------

// x [32,3,224,224] -> tb bf16 [6272][768]
__global__ void im2col_bf16_k(const float* __restrict__ x, ushort_t* __restrict__ out) {
    int idx = blockIdx.x * 256 + threadIdx.x;
    if (idx >= CROWS * DMODEL / 4) return;
    int r  = idx / (DMODEL / 4);
    int k4 = (idx - r * (DMODEL / 4)) * 4;
    int b = r / NPATCH, p = r - b * NPATCH;
    int py = p / 14, px = p - py * 14;
    int c = k4 >> 8, rem = k4 & 255, i = rem >> 4, j = rem & 15;
    const float* xp = x + (((size_t)(b * 3 + c) * 224) + py * 16 + i) * 224 + px * 16 + j;
    float4 v = *(const float4*)xp;
    ushort4 hv = {bf16rn(v.x), bf16rn(v.y), bf16rn(v.z), bf16rn(v.w)};
    *(ushort4*)(out + (size_t)r * DMODEL + k4) = hv;
}

// generic W fp32 -> bf16
__global__ void cvt_w_k(const float* __restrict__ W, ushort_t* __restrict__ out, int NK) {
    int idx = (blockIdx.x * 256 + threadIdx.x) * 4;
    if (idx >= NK) return;
    float4 v = *(const float4*)(W + idx);
    ushort4 hv = {bf16rn(v.x), bf16rn(v.y), bf16rn(v.z), bf16rn(v.w)};
    *(ushort4*)(out + idx) = hv;
}

// all 4 weight mats of one layer -> wl slab
__global__ void cvt_layer_k(const float* __restrict__ inW, const float* __restrict__ outW,
                            const float* __restrict__ fcW, const float* __restrict__ cpW,
                            ushort_t* __restrict__ wl) {
    size_t idx = ((size_t)blockIdx.x * 256 + threadIdx.x) * 4;
    if (idx >= WTOT) return;
    const float* src; size_t off;
    if (idx < WOFF_OUT)      { src = inW;  off = idx; }
    else if (idx < WOFF_FC)  { src = outW; off = idx - WOFF_OUT; }
    else if (idx < WOFF_CP)  { src = fcW;  off = idx - WOFF_FC; }
    else                     { src = cpW;  off = idx - WOFF_CP; }
    float4 v = *(const float4*)(src + off);
    ushort4 hv = {bf16rn(v.x), bf16rn(v.y), bf16rn(v.z), bf16rn(v.w)};
    *(ushort4*)(wl + idx) = hv;
}

// proj [768][512] -> pTs bf16 [512][768]
__global__ void cvt_pT_k(const float* __restrict__ proj, ushort_t* __restrict__ out) {
    int idx = blockIdx.x * 256 + threadIdx.x;
    if (idx >= DOUT * DMODEL) return;
    int n = idx / DMODEL, k = idx - n * DMODEL;
    out[(size_t)n * DMODEL + k] = bf16rn(proj[(size_t)k * DOUT + n]);
}

__global__ void embed_k(const float* __restrict__ conv, const float* __restrict__ cls,
                        const float* __restrict__ pos, float* __restrict__ h) {
    int idx = blockIdx.x * 256 + threadIdx.x;
    if (idx >= ROWS * DMODEL) return;
    int r = idx / DMODEL, d = idx - r * DMODEL;
    int b = r / NTOK, tok = r - b * NTOK;
    float v = (tok == 0) ? cls[d] : conv[((size_t)(b * NPATCH + tok - 1)) * DMODEL + d];
    h[idx] = v + pos[(size_t)tok * DMODEL + d];
}

__global__ void gauss_k(float* __restrict__ add) {
    int idx = blockIdx.x * 256 + threadIdx.x;
    if (idx >= NTOK * NTOK) return;
    int i = idx / NTOK, j = idx - i * NTOK;
    float v = 0.f;
    if (i > 0 && j > 0) {
        int p = i - 1, q = j - 1;
        int di = q / 14 - p / 14;
        int dj = q % 14 - p % 14;
        v = expf(-(float)(di * di + dj * dj) * 0.02f);
    }
    add[idx] = v;
}

// LayerNorm fp32 in-place (ln_pre)
__global__ __launch_bounds__(256) void ln768_k(const float* __restrict__ in, float* __restrict__ out,
                                               const float* __restrict__ w, const float* __restrict__ b) {
    int row = blockIdx.x, tid = threadIdx.x;
    const float* x = in + (size_t)row * DMODEL;
    float v0 = x[tid], v1 = x[tid + 256], v2 = x[tid + 512];
    float s = v0 + v1 + v2;
    float s2 = v0 * v0 + v1 * v1 + v2 * v2;
    for (int o = 32; o > 0; o >>= 1) { s += __shfl_down(s, o); s2 += __shfl_down(s2, o); }
    __shared__ float red[8];
    int wid = tid >> 6;
    if ((tid & 63) == 0) { red[wid] = s; red[4 + wid] = s2; }
    __syncthreads();
    s  = red[0] + red[1] + red[2] + red[3];
    s2 = red[4] + red[5] + red[6] + red[7];
    float mean = s * (1.0f / 768.0f);
    float var  = s2 * (1.0f / 768.0f) - mean * mean;
    float rinv = rsqrtf(var + 1e-5f);
    float* o_ = out + (size_t)row * DMODEL;
    o_[tid]       = (v0 - mean) * rinv * w[tid]       + b[tid];
    o_[tid + 256] = (v1 - mean) * rinv * w[tid + 256] + b[tid + 256];
    o_[tid + 512] = (v2 - mean) * rinv * w[tid + 512] + b[tid + 512];
}

// LayerNorm fp32 -> bf16
__global__ __launch_bounds__(256) void ln768_bf16_k(const float* __restrict__ in, ushort_t* __restrict__ out,
                                                    const float* __restrict__ w, const float* __restrict__ b) {
    int row = blockIdx.x, tid = threadIdx.x;
    const float* x = in + (size_t)row * DMODEL;
    float v0 = x[tid], v1 = x[tid + 256], v2 = x[tid + 512];
    float s = v0 + v1 + v2;
    float s2 = v0 * v0 + v1 * v1 + v2 * v2;
    for (int o = 32; o > 0; o >>= 1) { s += __shfl_down(s, o); s2 += __shfl_down(s2, o); }
    __shared__ float red[8];
    int wid = tid >> 6;
    if ((tid & 63) == 0) { red[wid] = s; red[4 + wid] = s2; }
    __syncthreads();
    s  = red[0] + red[1] + red[2] + red[3];
    s2 = red[4] + red[5] + red[6] + red[7];
    float mean = s * (1.0f / 768.0f);
    float var  = s2 * (1.0f / 768.0f) - mean * mean;
    float rinv = rsqrtf(var + 1e-5f);
    ushort_t* o_ = out + (size_t)row * DMODEL;
    o_[tid]       = bf16rn((v0 - mean) * rinv * w[tid]       + b[tid]);
    o_[tid + 256] = bf16rn((v1 - mean) * rinv * w[tid + 256] + b[tid + 256]);
    o_[tid + 512] = bf16rn((v2 - mean) * rinv * w[tid + 512] + b[tid + 512]);
}

// ---------------- pipelined MFMA GEMM:  C[M,N] (+)= A[M,K]bf16 @ W[N,K]bf16^T ----------------
// mode 0: C = r + bias (f32)
// mode 1: OS = bf16(quick_gelu(r + bias))
// mode 3: atomicAdd(C, r (+bias if blockIdx.z==0))   [split-K over gridDim.z]
// mode 4: OS = bf16(r + bias)
__global__ __launch_bounds__(256) void gemm_mfma_k(
    const ushort_t* __restrict__ A, const ushort_t* __restrict__ W,
    const float* __restrict__ bias, float* __restrict__ C, ushort_t* __restrict__ OS,
    int M, int N, int K, int mode)
{
    __shared__ ushort_t As[2][128][32];
    __shared__ ushort_t Bs[2][128][32];
    int tid = threadIdx.x;
    int lane = tid & 63;
    int wave = tid >> 6;
    int wm = wave >> 1, wn = wave & 1;
    int m0 = blockIdx.y * 128, n0 = blockIdx.x * 128;

    int klen = K / gridDim.z;
    int kbeg = blockIdx.z * klen;
    int nt = klen / 32;

    f32x4 acc[4][4];
    #pragma unroll
    for (int i = 0; i < 4; ++i)
        #pragma unroll
        for (int j = 0; j < 4; ++j)
            acc[i][j] = (f32x4){0.f, 0.f, 0.f, 0.f};

    int srow = tid >> 2;                                  // LDS row this lane fills
    int skq  = (((tid & 3) ^ ((tid >> 3) & 3)) * 8);      // pre-swizzled source slot
    int ar0 = m0 + srow;      if (ar0 > M - 1) ar0 = M - 1;
    int ar1 = m0 + srow + 64; if (ar1 > M - 1) ar1 = M - 1;
    const ushort_t* Ap0 = A + (size_t)ar0 * K + kbeg + skq;
    const ushort_t* Ap1 = A + (size_t)ar1 * K + kbeg + skq;
    const ushort_t* Wp0 = W + (size_t)(n0 + srow) * K + kbeg + skq;
    const ushort_t* Wp1 = W + (size_t)(n0 + srow + 64) * K + kbeg + skq;
    char* ldsA = (char*)As + tid * 16;
    char* ldsB = (char*)Bs + tid * 16;

    int fr = lane & 15, fq = lane >> 4;
    int rsl = (fq ^ ((fr >> 1) & 3)) * 8;                 // swizzled read slot

    // prologue: stage tile 0 into buffer 0
    GLL(Ap0, ldsA);
    GLL(Ap1, ldsA + 4096);
    GLL(Wp0, ldsB);
    GLL(Wp1, ldsB + 4096);

    for (int t = 0; t < nt; ++t) {
        int cur = t & 1;
        if (t + 1 < nt) {
            int nx = cur ^ 1;
            size_t ko = (size_t)(t + 1) * 32;
            GLL(Ap0 + ko, ldsA + nx * 8192);
            GLL(Ap1 + ko, ldsA + nx * 8192 + 4096);
            GLL(Wp0 + ko, ldsB + nx * 8192);
            GLL(Wp1 + ko, ldsB + nx * 8192 + 4096);
            asm volatile("s_waitcnt vmcnt(4)\n\ts_barrier" ::: "memory");
        } else {
            asm volatile("s_waitcnt vmcnt(0)\n\ts_barrier" ::: "memory");
        }
        bf16x8 a[4], b[4];
        #pragma unroll
        for (int fm = 0; fm < 4; ++fm)
            a[fm] = *(const bf16x8*)&As[cur][wm * 64 + fm * 16 + fr][rsl];
        #pragma unroll
        for (int fn = 0; fn < 4; ++fn)
            b[fn] = *(const bf16x8*)&Bs[cur][wn * 64 + fn * 16 + fr][rsl];
        #pragma unroll
        for (int fm = 0; fm < 4; ++fm)
            #pragma unroll
            for (int fn = 0; fn < 4; ++fn)
                acc[fm][fn] = __builtin_amdgcn_mfma_f32_16x16x32_bf16(a[fm], b[fn], acc[fm][fn], 0, 0, 0);
        asm volatile("s_barrier" ::: "memory");
    }

    // epilogue: D col = lane&15 (fr), row = fq*4 + j
    #pragma unroll
    for (int fn = 0; fn < 4; ++fn) {
        int ccol = n0 + wn * 64 + fn * 16 + fr;
        float bv = bias ? bias[ccol] : 0.f;
        if (mode == 3 && blockIdx.z != 0) bv = 0.f;
        #pragma unroll
        for (int fm = 0; fm < 4; ++fm) {
            int crow0 = m0 + wm * 64 + fm * 16 + fq * 4;
            #pragma unroll
            for (int j = 0; j < 4; ++j) {
                int row = crow0 + j;
                if (row < M) {
                    float v = acc[fm][fn][j] + bv;
                    if (mode == 0) {
                        C[(size_t)row * N + ccol] = v;
                    } else if (mode == 3) {
                        atomicAdd(&C[(size_t)row * N + ccol], v);
                    } else if (mode == 4) {
                        OS[(size_t)row * N + ccol] = bf16rn(v);
                    } else {
                        v = v / (1.0f + expf(-1.702f * v));
                        OS[(size_t)row * N + ccol] = bf16rn(v);
                    }
                }
            }
        }
    }
}

// ---------------- fused MFMA flash attention (bf16 qkv input) ----------------
__global__ __launch_bounds__(256) void attn_fused_k(
    const ushort_t* __restrict__ qkvb, ushort_t* __restrict__ out,
    const float* __restrict__ addition, int qoff)
{
    __shared__ ushort_t Ks[208][72];
    __shared__ ushort_t Vt[64][232];
    __shared__ ushort_t Pb[4][16][40];
    int tid = threadIdx.x;
    int bh = blockIdx.x;
    int b = bh / NHEAD, hh = bh - b * NHEAD;
    const ushort_t* base = qkvb + (size_t)b * NTOK * DQKV + hh * HDIM;

    // stage K [208][72] (zeros for t>=197) and V^T [64][232]
    {
        int tt = tid >> 4, dq = tid & 15;
        #pragma unroll
        for (int pass = 0; pass < 13; ++pass) {
            int t = pass * 16 + tt;
            ushort4 kv = {0, 0, 0, 0}, vv = {0, 0, 0, 0};
            if (t < NTOK) {
                kv = *(const ushort4*)(base + (size_t)t * DQKV + DMODEL + dq * 4);
                vv = *(const ushort4*)(base + (size_t)t * DQKV + 2 * DMODEL + dq * 4);
            }
            *(ushort4*)&Ks[t][dq * 4] = kv;
            Vt[dq * 4 + 0][t] = vv.x;
            Vt[dq * 4 + 1][t] = vv.y;
            Vt[dq * 4 + 2][t] = vv.z;
            Vt[dq * 4 + 3][t] = vv.w;
        }
        for (int z = tid; z < 64 * 24; z += 256) Vt[z / 24][208 + z % 24] = 0;
    }
    __syncthreads();

    int lane = tid & 63, wave = tid >> 6;
    int fr = lane & 15, fq = lane >> 4;

    for (int qt = wave; qt < 13; qt += 4) {
        int i0 = qt * 16;
        int qrow = i0 + fr; if (qrow > NTOK - 1) qrow = NTOK - 1;
        const ushort_t* qp = base + (size_t)qrow * DQKV + qoff + fq * 8;
        bf16x8 q0 = *(const bf16x8*)qp;
        bf16x8 q1 = *(const bf16x8*)(qp + 32);

        // ---- S = Q K^T
        f32x4 s[13];
        #pragma unroll
        for (int jt = 0; jt < 13; ++jt) {
            bf16x8 k0 = *(const bf16x8*)&Ks[jt * 16 + fr][fq * 8];
            bf16x8 k1 = *(const bf16x8*)&Ks[jt * 16 + fr][32 + fq * 8];
            f32x4 a = {0.f, 0.f, 0.f, 0.f};
            a = __builtin_amdgcn_mfma_f32_16x16x32_bf16(q0, k0, a, 0, 0, 0);
            a = __builtin_amdgcn_mfma_f32_16x16x32_bf16(q1, k1, a, 0, 0, 0);
            s[jt] = a;
        }

        // ---- softmax over j
        int irow[4];
        #pragma unroll
        for (int jj = 0; jj < 4; ++jj) {
            int ir = i0 + fq * 4 + jj;
            irow[jj] = (ir < NTOK) ? ir : (NTOK - 1);
        }
        float m[4] = {-1e30f, -1e30f, -1e30f, -1e30f};
        #pragma unroll
        for (int jt = 0; jt < 13; ++jt) {
            int jcol = jt * 16 + fr;
            #pragma unroll
            for (int jj = 0; jj < 4; ++jj) {
                float v = s[jt][jj] * 0.125f;
                if (addition) v += addition[irow[jj] * NTOK + (jcol < NTOK ? jcol : 0)];
                if (jcol >= NTOK) v = -1e30f;
                s[jt][jj] = v;
                m[jj] = fmaxf(m[jj], v);
            }
        }
        #pragma unroll
        for (int jj = 0; jj < 4; ++jj) {
            m[jj] = fmaxf(m[jj], __shfl_xor(m[jj], 1));
            m[jj] = fmaxf(m[jj], __shfl_xor(m[jj], 2));
            m[jj] = fmaxf(m[jj], __shfl_xor(m[jj], 4));
            m[jj] = fmaxf(m[jj], __shfl_xor(m[jj], 8));
        }
        float sum[4] = {0.f, 0.f, 0.f, 0.f};
        #pragma unroll
        for (int jt = 0; jt < 13; ++jt)
            #pragma unroll
            for (int jj = 0; jj < 4; ++jj) {
                float e = __expf(s[jt][jj] - m[jj]);
                s[jt][jj] = e;
                sum[jj] += e;
            }
        #pragma unroll
        for (int jj = 0; jj < 4; ++jj) {
            sum[jj] += __shfl_xor(sum[jj], 1);
            sum[jj] += __shfl_xor(sum[jj], 2);
            sum[jj] += __shfl_xor(sum[jj], 4);
            sum[jj] += __shfl_xor(sum[jj], 8);
        }
        float inv[4];
        #pragma unroll
        for (int jj = 0; jj < 4; ++jj) inv[jj] = 1.0f / sum[jj];

        // ---- O = P V : P staged bf16 through per-wave LDS (32 j per step)
        f32x4 o4[4];
        #pragma unroll
        for (int dt = 0; dt < 4; ++dt) o4[dt] = (f32x4){0.f, 0.f, 0.f, 0.f};
        for (int st = 0; st < 7; ++st) {
            #pragma unroll
            for (int half = 0; half < 2; ++half) {
                int jt = st * 2 + half;
                #pragma unroll
                for (int jj = 0; jj < 4; ++jj) {
                    ushort_t pv = 0;
                    if (jt < 13) pv = bf16rn(s[jt][jj] * inv[jj]);
                    Pb[wave][fq * 4 + jj][half * 16 + fr] = pv;
                }
            }
            asm volatile("s_waitcnt lgkmcnt(0)" ::: "memory");
            bf16x8 pa = *(const bf16x8*)&Pb[wave][fr][fq * 8];
            #pragma unroll
            for (int dt = 0; dt < 4; ++dt) {
                bf16x8 vf = *(const bf16x8*)&Vt[dt * 16 + fr][st * 32 + fq * 8];
                o4[dt] = __builtin_amdgcn_mfma_f32_16x16x32_bf16(pa, vf, o4[dt], 0, 0, 0);
            }
        }

        // ---- write O bf16
        #pragma unroll
        for (int jj = 0; jj < 4; ++jj) {
            int ir = i0 + fq * 4 + jj;
            if (ir < NTOK) {
                ushort_t* op = out + ((size_t)(b * NTOK + ir)) * DMODEL + hh * HDIM + fr;
                #pragma unroll
                for (int dt = 0; dt < 4; ++dt)
                    op[dt * 16] = bf16rn(o4[dt][jj]);
            }
        }
    }
}

// ---------------- launch ----------------
extern "C" void kernel_launch(void* const* d_in, const int* in_sizes, int n_in,
                              void* d_out, int out_size, void* d_ws, size_t ws_size,
                              hipStream_t stream) {
    const float* x        = (const float*)d_in[0];
    const float* conv1_w  = (const float*)d_in[1];
    const float* cls      = (const float*)d_in[2];
    const float* pos      = (const float*)d_in[3];
    const float* ln_pre_w = (const float*)d_in[4];
    const float* ln_pre_b = (const float*)d_in[5];
    const float* in_proj_w  = (const float*)d_in[6];
    const float* in_proj_b  = (const float*)d_in[7];
    const float* out_proj_w = (const float*)d_in[8];
    const float* out_proj_b = (const float*)d_in[9];
    const float* ln1_w = (const float*)d_in[10];
    const float* ln1_b = (const float*)d_in[11];
    const float* ln2_w = (const float*)d_in[12];
    const float* ln2_b = (const float*)d_in[13];
    const float* fc_w  = (const float*)d_in[14];
    const float* fc_b  = (const float*)d_in[15];
    const float* cproj_w = (const float*)d_in[16];
    const float* cproj_b = (const float*)d_in[17];
    const float* ln_post_w = (const float*)d_in[18];
    const float* ln_post_b = (const float*)d_in[19];
    const float* proj = (const float*)d_in[20];
    float* out = (float*)d_out;

    float* ws   = (float*)d_ws;
    float* h    = ws + WS_H;
    float* ctmp = ws + WS_QKVB;                 // conv f32 tmp (aliases qkvb)
    ushort_t* qkvb = (ushort_t*)(ws + WS_QKVB);
    ushort_t* gb   = (ushort_t*)(ws + WS_GB);
    ushort_t* tb   = (ushort_t*)(ws + WS_TB);
    ushort_t* wl   = (ushort_t*)(ws + WS_WL);
    ushort_t* pTs  = (ushort_t*)(ws + WS_PTS);
    float* add  = ws + WS_ADD;

    // patch embedding
    im2col_bf16_k<<<(CROWS * DMODEL / 4 + 255) / 256, 256, 0, stream>>>(x, tb);
    cvt_w_k<<<(DMODEL * DMODEL / 4 + 255) / 256, 256, 0, stream>>>(conv1_w, wl, DMODEL * DMODEL);
    gemm_mfma_k<<<dim3(DMODEL / 128, (CROWS + 127) / 128), 256, 0, stream>>>(
        tb, wl, nullptr, ctmp, nullptr, CROWS, DMODEL, DMODEL, 0);
    embed_k<<<(ROWS * DMODEL + 255) / 256, 256, 0, stream>>>(ctmp, cls, pos, h);
    ln768_k<<<ROWS, 256, 0, stream>>>(h, h, ln_pre_w, ln_pre_b);
    gauss_k<<<(NTOK * NTOK + 255) / 256, 256, 0, stream>>>(add);
    cvt_pT_k<<<(DOUT * DMODEL + 255) / 256, 256, 0, stream>>>(proj, pTs);

    const int GY = (ROWS + 127) / 128;  // 50
    for (int l = 0; l < NLAYER; ++l) {
        cvt_layer_k<<<(int)(WTOT / 4 / 256), 256, 0, stream>>>(
            in_proj_w + (size_t)l * DQKV * DMODEL, out_proj_w + (size_t)l * DMODEL * DMODEL,
            fc_w + (size_t)l * DFF * DMODEL, cproj_w + (size_t)l * DMODEL * DFF, wl);
        ln768_bf16_k<<<ROWS, 256, 0, stream>>>(h, tb, ln1_w + l * DMODEL, ln1_b + l * DMODEL);
        gemm_mfma_k<<<dim3(DQKV / 128, GY), 256, 0, stream>>>(
            tb, wl + WOFF_IN, in_proj_b + (size_t)l * DQKV, nullptr, qkvb, ROWS, DQKV, DMODEL, 4);
        bool nac = (l == NLAYER - 1);
        attn_fused_k<<<NBH, 256, 0, stream>>>(qkvb, tb, nac ? add : nullptr, nac ? DMODEL : 0);
        gemm_mfma_k<<<dim3(DMODEL / 128, GY, 2), 256, 0, stream>>>(
            tb, wl + WOFF_OUT, out_proj_b + (size_t)l * DMODEL, h, nullptr, ROWS, DMODEL, DMODEL, 3);
        ln768_bf16_k<<<ROWS, 256, 0, stream>>>(h, tb, ln2_w + l * DMODEL, ln2_b + l * DMODEL);
        gemm_mfma_k<<<dim3(DFF / 128, GY), 256, 0, stream>>>(
            tb, wl + WOFF_FC, fc_b + (size_t)l * DFF, nullptr, gb, ROWS, DFF, DMODEL, 1);
        gemm_mfma_k<<<dim3(DMODEL / 128, GY, 2), 256, 0, stream>>>(
            gb, wl + WOFF_CP, cproj_b + (size_t)l * DMODEL, h, nullptr, ROWS, DMODEL, DFF, 3);
    }

    ln768_bf16_k<<<ROWS, 256, 0, stream>>>(h, tb, ln_post_w, ln_post_b);
    gemm_mfma_k<<<dim3(DOUT / 128, GY), 256, 0, stream>>>(
        tb, pTs, nullptr, out, nullptr, ROWS, DOUT, DMODEL, 0);
}